// Round 2
// baseline (5387.281 us; speedup 1.0000x reference)
//
#include <hip/hip_runtime.h>
#include <hip/hip_bf16.h>
#include <math.h>

// Problem constants
constexpr int S   = 2048;
constexpr int D   = 2048;
constexpr int H   = 16;
constexpr int KVH = 4;
constexpr int HD  = 128;
constexpr int NQ  = H * HD;    // 2048
constexpr int NKV = KVH * HD;  // 512
constexpr int GROUPS = H / KVH; // 4
constexpr float SCALE = 0.088388347648318447f; // 128^-0.5
constexpr int HEAVY  = 204;          // int(0.1*2048)
constexpr int RECENT = 204;
constexpr int SKEEP  = S - RECENT;   // 1844
constexpr int MASKC  = S + 1;        // 2049

// ---------------------------------------------------------------------------
// GEMM 1: C[M,N] (fp32) = A[M,K] (fp32) @ W[K,N] (fp32) + bias[N] (fp32)
// 64x64 tile, 256 threads, 4x4 per-thread microtile, BK=16
// ---------------------------------------------------------------------------
__global__ __launch_bounds__(256) void gemm_f32_bias(
    const float* __restrict__ A, const float* __restrict__ W,
    const float* __restrict__ bias, float* __restrict__ C,
    int M, int N, int Kd) {
  __shared__ float As[16][65];
  __shared__ float Bs[16][65];
  const int tid = threadIdx.x;
  const int tx = tid & 15, ty = tid >> 4;
  const int row0 = blockIdx.y * 64, col0 = blockIdx.x * 64;
  float acc[4][4] = {};
  for (int k0 = 0; k0 < Kd; k0 += 16) {
    for (int i = tid; i < 64 * 16; i += 256) {
      int m = i >> 4, kk = i & 15;
      As[kk][m] = A[(size_t)(row0 + m) * Kd + k0 + kk];
    }
    for (int i = tid; i < 16 * 64; i += 256) {
      int kk = i >> 6, n = i & 63;
      Bs[kk][n] = W[(size_t)(k0 + kk) * N + col0 + n];
    }
    __syncthreads();
#pragma unroll
    for (int kk = 0; kk < 16; ++kk) {
      float a[4], b[4];
#pragma unroll
      for (int i = 0; i < 4; ++i) a[i] = As[kk][ty * 4 + i];
#pragma unroll
      for (int j = 0; j < 4; ++j) b[j] = Bs[kk][tx * 4 + j];
#pragma unroll
      for (int i = 0; i < 4; ++i)
#pragma unroll
        for (int j = 0; j < 4; ++j) acc[i][j] += a[i] * b[j];
    }
    __syncthreads();
  }
#pragma unroll
  for (int i = 0; i < 4; ++i) {
#pragma unroll
    for (int j = 0; j < 4; ++j) {
      int r = row0 + ty * 4 + i, c = col0 + tx * 4 + j;
      C[(size_t)r * N + c] = acc[i][j] + bias[c];
    }
  }
}

// ---------------------------------------------------------------------------
// GEMM 2: C[M,N] (fp32) = A[M,K] (fp32) @ W[K,N] (fp32)   (output projection)
// ---------------------------------------------------------------------------
__global__ __launch_bounds__(256) void gemm_f32_out(
    const float* __restrict__ A, const float* __restrict__ W,
    float* __restrict__ C, int M, int N, int Kd) {
  __shared__ float As[16][65];
  __shared__ float Bs[16][65];
  const int tid = threadIdx.x;
  const int tx = tid & 15, ty = tid >> 4;
  const int row0 = blockIdx.y * 64, col0 = blockIdx.x * 64;
  float acc[4][4] = {};
  for (int k0 = 0; k0 < Kd; k0 += 16) {
    for (int i = tid; i < 64 * 16; i += 256) {
      int m = i >> 4, kk = i & 15;
      As[kk][m] = A[(size_t)(row0 + m) * Kd + k0 + kk];
    }
    for (int i = tid; i < 16 * 64; i += 256) {
      int kk = i >> 6, n = i & 63;
      Bs[kk][n] = W[(size_t)(k0 + kk) * N + col0 + n];
    }
    __syncthreads();
#pragma unroll
    for (int kk = 0; kk < 16; ++kk) {
      float a[4], b[4];
#pragma unroll
      for (int i = 0; i < 4; ++i) a[i] = As[kk][ty * 4 + i];
#pragma unroll
      for (int j = 0; j < 4; ++j) b[j] = Bs[kk][tx * 4 + j];
#pragma unroll
      for (int i = 0; i < 4; ++i)
#pragma unroll
        for (int j = 0; j < 4; ++j) acc[i][j] += a[i] * b[j];
    }
    __syncthreads();
  }
#pragma unroll
  for (int i = 0; i < 4; ++i) {
#pragma unroll
    for (int j = 0; j < 4; ++j) {
      int r = row0 + ty * 4 + i, c = col0 + tx * 4 + j;
      C[(size_t)r * N + c] = acc[i][j];
    }
  }
}

// ---------------------------------------------------------------------------
// Flash attention: one block per (q-tile of 64, head). fp32 throughout.
// Writes AO[(q, h*HD+d)] = out, and per-row m, l for the cur_scores pass.
// ---------------------------------------------------------------------------
__global__ __launch_bounds__(256) void attn_kernel(
    const float* __restrict__ Q, const float* __restrict__ K,
    const float* __restrict__ V, float* __restrict__ AO,
    float* __restrict__ mbuf, float* __restrict__ lbuf) {
  const int qt = blockIdx.x, h = blockIdx.y;
  const int kvh = h / GROUPS;
  const int tid = threadIdx.x;
  const int q0 = qt * 64;

  __shared__ float Qs[64][HD + 1];
  __shared__ float Ks[64][HD + 1];
  __shared__ float Vs[64][HD + 1];
  __shared__ float Ps[64][65];
  __shared__ float mrow[64], lrow[64], arow[64];

  for (int i = tid; i < 64 * HD; i += 256) {
    int r = i >> 7, d = i & 127;
    Qs[r][d] = Q[(size_t)(q0 + r) * NQ + h * HD + d];
  }
  if (tid < 64) { mrow[tid] = -INFINITY; lrow[tid] = 0.f; }

  const int qr = tid >> 2;
  const int seg = tid & 3;
  const int c0 = seg * 16;
  const int d0 = seg * 32;
  const int qg = q0 + qr;
  float o[32];
#pragma unroll
  for (int i = 0; i < 32; ++i) o[i] = 0.f;

  for (int kt = 0; kt <= qt; ++kt) {
    __syncthreads();  // protects Ks/Vs/Ps reuse + first-iter Qs/mrow
    for (int i = tid; i < 64 * HD; i += 256) {
      int r = i >> 7, d = i & 127;
      size_t base = (size_t)(kt * 64 + r) * NKV + kvh * HD + d;
      Ks[r][d] = K[base];
      Vs[r][d] = V[base];
    }
    __syncthreads();
    // S tile: 16 columns per thread
    float acc[16];
#pragma unroll
    for (int c = 0; c < 16; ++c) acc[c] = 0.f;
    for (int d = 0; d < HD; ++d) {
      float qv = Qs[qr][d];
#pragma unroll
      for (int c = 0; c < 16; ++c) acc[c] += qv * Ks[c0 + c][d];
    }
#pragma unroll
    for (int c = 0; c < 16; ++c) {
      int kg = kt * 64 + c0 + c;
      Ps[qr][c0 + c] = (kg <= qg) ? acc[c] * SCALE : -INFINITY;
    }
    __syncthreads();
    // online softmax, one thread per row
    if (tid < 64) {
      int r = tid;
      float mold = mrow[r];
      float mx = mold;
      for (int c = 0; c < 64; ++c) mx = fmaxf(mx, Ps[r][c]);
      float al = __expf(mold - mx);
      float sum = 0.f;
      for (int c = 0; c < 64; ++c) {
        float p = __expf(Ps[r][c] - mx);
        Ps[r][c] = p;
        sum += p;
      }
      mrow[r] = mx;
      lrow[r] = lrow[r] * al + sum;
      arow[r] = al;
    }
    __syncthreads();
    float al = arow[qr];
#pragma unroll
    for (int d = 0; d < 32; ++d) o[d] *= al;
    for (int c = 0; c < 64; ++c) {
      float p = Ps[qr][c];
#pragma unroll
      for (int d = 0; d < 32; ++d) o[d] += p * Vs[c][d0 + d];
    }
  }
  __syncthreads();
  float inv = 1.0f / lrow[qr];
#pragma unroll
  for (int d = 0; d < 32; ++d) {
    AO[(size_t)qg * NQ + h * HD + d0 + d] = o[d] * inv;
  }
  if (tid < 64) {
    mbuf[h * S + q0 + tid] = mrow[tid];
    lbuf[h * S + q0 + tid] = lrow[tid];
  }
}

// ---------------------------------------------------------------------------
// cur_scores: one block per (k-tile of 64, head).
// cur[h][k] = sum_q exp(s[q,k]-m_q)/l_q over causal region.
// ---------------------------------------------------------------------------
__global__ __launch_bounds__(256) void cur_kernel(
    const float* __restrict__ Q, const float* __restrict__ K,
    const float* __restrict__ mbuf, const float* __restrict__ lbuf,
    float* __restrict__ cur) {
  const int kt = blockIdx.x, h = blockIdx.y;
  const int kvh = h / GROUPS;
  const int tid = threadIdx.x;

  __shared__ float Qs[64][HD + 1];
  __shared__ float Ks[64][HD + 1];
  __shared__ float Ps[64][65];
  __shared__ float mq[64], linv[64];

  for (int i = tid; i < 64 * HD; i += 256) {
    int r = i >> 7, d = i & 127;
    Ks[r][d] = K[(size_t)(kt * 64 + r) * NKV + kvh * HD + d];
  }
  const int qr = tid >> 2;
  const int seg = tid & 3;
  const int c0 = seg * 16;
  float csum = 0.f;

  for (int qt = kt; qt < S / 64; ++qt) {
    __syncthreads();
    for (int i = tid; i < 64 * HD; i += 256) {
      int r = i >> 7, d = i & 127;
      Qs[r][d] = Q[(size_t)(qt * 64 + r) * NQ + h * HD + d];
    }
    if (tid < 64) {
      mq[tid] = mbuf[h * S + qt * 64 + tid];
      linv[tid] = 1.0f / lbuf[h * S + qt * 64 + tid];
    }
    __syncthreads();
    float acc[16];
#pragma unroll
    for (int c = 0; c < 16; ++c) acc[c] = 0.f;
    for (int d = 0; d < HD; ++d) {
      float qv = Qs[qr][d];
#pragma unroll
      for (int c = 0; c < 16; ++c) acc[c] += qv * Ks[c0 + c][d];
    }
    const int qg = qt * 64 + qr;
#pragma unroll
    for (int c = 0; c < 16; ++c) {
      int kg = kt * 64 + c0 + c;
      Ps[qr][c0 + c] =
          (kg <= qg) ? __expf(acc[c] * SCALE - mq[qr]) * linv[qr] : 0.f;
    }
    __syncthreads();
    if (tid < 64) {
      float s = 0.f;
      for (int r = 0; r < 64; ++r) s += Ps[r][tid];
      csum += s;
    }
    __syncthreads();
  }
  if (tid < 64) {
    int kg = kt * 64 + tid;
    if (kg < S) cur[h * S + kg] = csum;
  }
}

// ---------------------------------------------------------------------------
// top-k + mask: one block per head. Exact jax.lax.top_k semantics
// (ties broken toward lower index) via binary search on uint float bits
// (cur values are strictly positive, so uint order == float order).
// ---------------------------------------------------------------------------
__global__ __launch_bounds__(256) void topk_kernel(
    const float* __restrict__ cur, float* __restrict__ mask) {
  const int h = blockIdx.x;
  const int tid = threadIdx.x;
  __shared__ unsigned uv[SKEEP];
  __shared__ int red[256];

  for (int i = tid; i < SKEEP; i += 256) uv[i] = __float_as_uint(cur[h * S + i]);
  __syncthreads();

  unsigned lo = 0u, hi = 0xffffffffu;
  while (lo < hi) {
    unsigned mid = (unsigned)((((unsigned long long)lo + hi) + 1ull) >> 1);
    int c = 0;
    for (int i = tid; i < SKEEP; i += 256) c += (uv[i] >= mid) ? 1 : 0;
    red[tid] = c;
    __syncthreads();
    for (int s = 128; s > 0; s >>= 1) {
      if (tid < s) red[tid] += red[tid + s];
      __syncthreads();
    }
    int cnt = red[0];
    __syncthreads();
    if (cnt >= HEAVY) lo = mid; else hi = mid - 1;
  }
  const unsigned vk = lo;
  int c = 0;
  for (int i = tid; i < SKEEP; i += 256) c += (uv[i] > vk) ? 1 : 0;
  red[tid] = c;
  __syncthreads();
  for (int s = 128; s > 0; s >>= 1) {
    if (tid < s) red[tid] += red[tid + s];
    __syncthreads();
  }
  const int cgt = red[0];
  __syncthreads();
  const int r = HEAVY - cgt;  // >= 0 tie slots to fill in index order

  for (int j = tid; j < MASKC; j += 256)
    mask[(size_t)h * MASKC + j] = (j >= MASKC - RECENT) ? 1.0f : 0.0f;
  __syncthreads();
  for (int i = tid; i < SKEEP; i += 256)
    if (uv[i] > vk) mask[(size_t)h * MASKC + i] = 1.0f;
  if (tid == 0) {
    int rem = r;
    for (int i = 0; i < SKEEP && rem > 0; ++i) {
      if (uv[i] == vk) { mask[(size_t)h * MASKC + i] = 1.0f; --rem; }
    }
  }
}

// ---------------------------------------------------------------------------
extern "C" void kernel_launch(void* const* d_in, const int* in_sizes, int n_in,
                              void* d_out, int out_size, void* d_ws,
                              size_t ws_size, hipStream_t stream) {
  const float* hs  = (const float*)d_in[0];
  const float* q_w = (const float*)d_in[1];
  const float* q_b = (const float*)d_in[2];
  const float* k_w = (const float*)d_in[3];
  const float* k_b = (const float*)d_in[4];
  const float* v_w = (const float*)d_in[5];
  const float* v_b = (const float*)d_in[6];
  const float* o_w = (const float*)d_in[7];

  float* ws = (float*)d_ws;
  float* Qw  = ws;                             // S*NQ  = 4,194,304
  float* Kw  = Qw + (size_t)S * NQ;            // S*NKV = 1,048,576
  float* Vw  = Kw + (size_t)S * NKV;           // S*NKV
  float* AO  = Vw + (size_t)S * NKV;           // S*NQ
  float* mb  = AO + (size_t)S * NQ;            // H*S
  float* lb  = mb + (size_t)H * S;             // H*S
  float* cur = lb + (size_t)H * S;             // H*S

  float* outp  = (float*)d_out;
  float* maskp = outp + (size_t)S * D;

  dim3 blk(256);
  gemm_f32_bias<<<dim3(NQ / 64, S / 64), blk, 0, stream>>>(hs, q_w, q_b, Qw, S, NQ, D);
  gemm_f32_bias<<<dim3(NKV / 64, S / 64), blk, 0, stream>>>(hs, k_w, k_b, Kw, S, NKV, D);
  gemm_f32_bias<<<dim3(NKV / 64, S / 64), blk, 0, stream>>>(hs, v_w, v_b, Vw, S, NKV, D);
  attn_kernel<<<dim3(S / 64, H), blk, 0, stream>>>(Qw, Kw, Vw, AO, mb, lb);
  cur_kernel<<<dim3((SKEEP + 63) / 64, H), blk, 0, stream>>>(Qw, Kw, mb, lb, cur);
  topk_kernel<<<dim3(H), blk, 0, stream>>>(cur, maskp);
  gemm_f32_out<<<dim3(D / 64, S / 64), blk, 0, stream>>>(AO, o_w, outp, S, D, NQ);
}

// Round 3
// 4141.459 us; speedup vs baseline: 1.3008x; 1.3008x over previous
//
#include <hip/hip_runtime.h>
#include <hip/hip_bf16.h>
#include <math.h>

// Problem constants
constexpr int S   = 2048;
constexpr int D   = 2048;
constexpr int H   = 16;
constexpr int KVH = 4;
constexpr int HD  = 128;
constexpr int NQ  = H * HD;      // 2048
constexpr int NKV = KVH * HD;    // 512
constexpr int N3  = NQ + 2 * NKV; // 3072 fused QKV columns
constexpr int KOFF = NQ;          // 2048
constexpr int VOFF = NQ + NKV;    // 2560
constexpr int GROUPS = H / KVH;   // 4
constexpr float SCALE = 0.088388347648318447f; // 128^-0.5
constexpr int HEAVY  = 204;
constexpr int RECENT = 204;
constexpr int SKEEP  = S - RECENT;  // 1844
constexpr int MASKC  = S + 1;       // 2049

typedef short bf16x8 __attribute__((ext_vector_type(8)));
typedef unsigned short ushort8 __attribute__((ext_vector_type(8)));
typedef float f32x4 __attribute__((ext_vector_type(4)));

__device__ __forceinline__ unsigned short f2b(float x) {
  __hip_bfloat16 h = __float2bfloat16(x);
  return *(unsigned short*)&h;
}
__device__ __forceinline__ float b2f(unsigned short u) {
  __hip_bfloat16 h = *(__hip_bfloat16*)&u;
  return __bfloat162float(h);
}

// ---------------------------------------------------------------------------
// split_act: fp32 [n] -> bf16 hi/lo pair
// ---------------------------------------------------------------------------
__global__ __launch_bounds__(256) void split_act(
    const float* __restrict__ in, unsigned short* __restrict__ oh,
    unsigned short* __restrict__ ol, int n) {
  for (int i = blockIdx.x * 256 + threadIdx.x; i < n; i += gridDim.x * 256) {
    float x = in[i];
    unsigned short h = f2b(x);
    float rem = x - b2f(h);
    oh[i] = h;
    ol[i] = f2b(rem);
  }
}

// ---------------------------------------------------------------------------
// split_wT: in[K][N] fp32 -> out[rowOff + n][k] bf16 hi/lo (transposed split)
// 64x64 LDS tile transpose. grid = (N/64, K/64), block 256.
// ---------------------------------------------------------------------------
__global__ __launch_bounds__(256) void split_wT(
    const float* __restrict__ in, unsigned short* __restrict__ oh,
    unsigned short* __restrict__ ol, int K, int N, int rowOff, int ldOut) {
  __shared__ float Lt[64][65];
  const int n0 = blockIdx.x * 64, k0 = blockIdx.y * 64;
  const int t = threadIdx.x;
  const int cq = t & 15, r4 = t >> 4;
#pragma unroll
  for (int i = 0; i < 4; ++i) {
    int r = r4 + i * 16;  // k row
    float4 v = *(const float4*)&in[(size_t)(k0 + r) * N + n0 + cq * 4];
    Lt[cq * 4 + 0][r] = v.x;
    Lt[cq * 4 + 1][r] = v.y;
    Lt[cq * 4 + 2][r] = v.z;
    Lt[cq * 4 + 3][r] = v.w;
  }
  __syncthreads();
#pragma unroll
  for (int i = 0; i < 4; ++i) {
    int rr = r4 + i * 16;  // n row of output
    size_t base = (size_t)(rowOff + n0 + rr) * ldOut + k0 + cq * 4;
#pragma unroll
    for (int j = 0; j < 4; ++j) {
      float x = Lt[rr][cq * 4 + j];
      unsigned short h = f2b(x);
      oh[base + j] = h;
      ol[base + j] = f2b(x - b2f(h));
    }
  }
}

// ---------------------------------------------------------------------------
// concat_bias: [q_b | k_b | v_b] -> bias[3072]
// ---------------------------------------------------------------------------
__global__ void concat_bias(const float* qb, const float* kb, const float* vb,
                            float* out) {
  int i = blockIdx.x * 256 + threadIdx.x;
  if (i < NQ) out[i] = qb[i];
  else if (i < VOFF) out[i] = kb[i - KOFF];
  else if (i < N3) out[i] = vb[i - VOFF];
}

// ---------------------------------------------------------------------------
// Split-bf16 MFMA GEMM: C[M][N] fp32 = A[M][K] @ B^T[N][K] (+bias)
// where A,B given as bf16 (hi,lo); computes Ah*Bh + Ah*Bl + Al*Bh.
// 128x128 tile, 256 threads (4 waves, 2x2), 16x16x32 MFMA, BK=32.
// LDS rows padded to 40 shorts (80 B, 16B-aligned, 2-way bank alias = free).
// ---------------------------------------------------------------------------
__global__ __launch_bounds__(256) void gemm_split(
    const unsigned short* __restrict__ Ah, const unsigned short* __restrict__ Al,
    const unsigned short* __restrict__ Bh, const unsigned short* __restrict__ Bl,
    const float* __restrict__ bias, float* __restrict__ C,
    int M, int N, int K) {
  __shared__ __align__(16) unsigned short sAh[128 * 40];
  __shared__ __align__(16) unsigned short sAl[128 * 40];
  __shared__ __align__(16) unsigned short sBh[128 * 40];
  __shared__ __align__(16) unsigned short sBl[128 * 40];
  const int tid = threadIdx.x;
  const int lane = tid & 63, wave = tid >> 6;
  const int wm = wave >> 1, wn = wave & 1;
  const int quad = lane >> 4, l16 = lane & 15;
  const int m0 = blockIdx.y * 128, n0 = blockIdx.x * 128;

  f32x4 acc[4][4];
#pragma unroll
  for (int i = 0; i < 4; ++i)
#pragma unroll
    for (int j = 0; j < 4; ++j) acc[i][j] = (f32x4){0.f, 0.f, 0.f, 0.f};

  for (int k0 = 0; k0 < K; k0 += 32) {
#pragma unroll
    for (int it = 0; it < 2; ++it) {
      int c = tid + it * 256;
      int r = c >> 2, sub = c & 3;
      size_t ga = (size_t)(m0 + r) * K + k0 + sub * 8;
      size_t gb = (size_t)(n0 + r) * K + k0 + sub * 8;
      int li = r * 40 + sub * 8;
      *(ushort8*)&sAh[li] = *(const ushort8*)&Ah[ga];
      *(ushort8*)&sAl[li] = *(const ushort8*)&Al[ga];
      *(ushort8*)&sBh[li] = *(const ushort8*)&Bh[gb];
      *(ushort8*)&sBl[li] = *(const ushort8*)&Bl[gb];
    }
    __syncthreads();
    bf16x8 fah[4], fal[4], fbh[4], fbl[4];
#pragma unroll
    for (int i = 0; i < 4; ++i) {
      int ra = (wm * 64 + i * 16 + l16) * 40 + quad * 8;
      fah[i] = *(bf16x8*)&sAh[ra];
      fal[i] = *(bf16x8*)&sAl[ra];
      int rb = (wn * 64 + i * 16 + l16) * 40 + quad * 8;
      fbh[i] = *(bf16x8*)&sBh[rb];
      fbl[i] = *(bf16x8*)&sBl[rb];
    }
#pragma unroll
    for (int i = 0; i < 4; ++i)
#pragma unroll
      for (int j = 0; j < 4; ++j) {
        acc[i][j] = __builtin_amdgcn_mfma_f32_16x16x32_bf16(fah[i], fbh[j], acc[i][j], 0, 0, 0);
        acc[i][j] = __builtin_amdgcn_mfma_f32_16x16x32_bf16(fah[i], fbl[j], acc[i][j], 0, 0, 0);
        acc[i][j] = __builtin_amdgcn_mfma_f32_16x16x32_bf16(fal[i], fbh[j], acc[i][j], 0, 0, 0);
      }
    __syncthreads();
  }
  // epilogue: D col = lane&15, row = quad*4 + reg
#pragma unroll
  for (int i = 0; i < 4; ++i) {
#pragma unroll
    for (int j = 0; j < 4; ++j) {
      int row = m0 + wm * 64 + i * 16 + quad * 4;
      int col = n0 + wn * 64 + j * 16 + l16;
      float bv = bias ? bias[col] : 0.0f;
#pragma unroll
      for (int r = 0; r < 4; ++r) {
        C[(size_t)(row + r) * N + col] = acc[i][j][r] + bv;
      }
    }
  }
}

// ---------------------------------------------------------------------------
// Flash attention (fp32 VALU, unchanged numerics): one block per (64 q, head).
// Reads fused QKV buffer [S][N3].
// ---------------------------------------------------------------------------
__global__ __launch_bounds__(256) void attn_kernel(
    const float* __restrict__ QKV, float* __restrict__ AO,
    float* __restrict__ mbuf, float* __restrict__ lbuf) {
  const int qt = blockIdx.x, h = blockIdx.y;
  const int kvh = h / GROUPS;
  const int tid = threadIdx.x;
  const int q0 = qt * 64;

  __shared__ float Qs[64][HD + 1];
  __shared__ float Ks[64][HD + 1];
  __shared__ float Vs[64][HD + 1];
  __shared__ float Ps[64][65];
  __shared__ float mrow[64], lrow[64], arow[64];

  for (int i = tid; i < 64 * HD; i += 256) {
    int r = i >> 7, d = i & 127;
    Qs[r][d] = QKV[(size_t)(q0 + r) * N3 + h * HD + d];
  }
  if (tid < 64) { mrow[tid] = -INFINITY; lrow[tid] = 0.f; }

  const int qr = tid >> 2;
  const int seg = tid & 3;
  const int c0 = seg * 16;
  const int d0 = seg * 32;
  const int qg = q0 + qr;
  float o[32];
#pragma unroll
  for (int i = 0; i < 32; ++i) o[i] = 0.f;

  for (int kt = 0; kt <= qt; ++kt) {
    __syncthreads();
    for (int i = tid; i < 64 * HD; i += 256) {
      int r = i >> 7, d = i & 127;
      size_t base = (size_t)(kt * 64 + r) * N3 + kvh * HD + d;
      Ks[r][d] = QKV[base + KOFF];
      Vs[r][d] = QKV[base + VOFF];
    }
    __syncthreads();
    float acc[16];
#pragma unroll
    for (int c = 0; c < 16; ++c) acc[c] = 0.f;
    for (int d = 0; d < HD; ++d) {
      float qv = Qs[qr][d];
#pragma unroll
      for (int c = 0; c < 16; ++c) acc[c] += qv * Ks[c0 + c][d];
    }
#pragma unroll
    for (int c = 0; c < 16; ++c) {
      int kg = kt * 64 + c0 + c;
      Ps[qr][c0 + c] = (kg <= qg) ? acc[c] * SCALE : -INFINITY;
    }
    __syncthreads();
    if (tid < 64) {
      int r = tid;
      float mold = mrow[r];
      float mx = mold;
      for (int c = 0; c < 64; ++c) mx = fmaxf(mx, Ps[r][c]);
      float al = __expf(mold - mx);
      float sum = 0.f;
      for (int c = 0; c < 64; ++c) {
        float p = __expf(Ps[r][c] - mx);
        Ps[r][c] = p;
        sum += p;
      }
      mrow[r] = mx;
      lrow[r] = lrow[r] * al + sum;
      arow[r] = al;
    }
    __syncthreads();
    float al = arow[qr];
#pragma unroll
    for (int d = 0; d < 32; ++d) o[d] *= al;
    for (int c = 0; c < 64; ++c) {
      float p = Ps[qr][c];
#pragma unroll
      for (int d = 0; d < 32; ++d) o[d] += p * Vs[c][d0 + d];
    }
  }
  __syncthreads();
  float inv = 1.0f / lrow[qr];
#pragma unroll
  for (int d = 0; d < 32; ++d) {
    AO[(size_t)qg * NQ + h * HD + d0 + d] = o[d] * inv;
  }
  if (tid < 64) {
    mbuf[h * S + q0 + tid] = mrow[tid];
    lbuf[h * S + q0 + tid] = lrow[tid];
  }
}

// ---------------------------------------------------------------------------
// cur_scores (unchanged numerics, fused QKV input)
// ---------------------------------------------------------------------------
__global__ __launch_bounds__(256) void cur_kernel(
    const float* __restrict__ QKV, const float* __restrict__ mbuf,
    const float* __restrict__ lbuf, float* __restrict__ cur) {
  const int kt = blockIdx.x, h = blockIdx.y;
  const int kvh = h / GROUPS;
  const int tid = threadIdx.x;

  __shared__ float Qs[64][HD + 1];
  __shared__ float Ks[64][HD + 1];
  __shared__ float Ps[64][65];
  __shared__ float mq[64], linv[64];

  for (int i = tid; i < 64 * HD; i += 256) {
    int r = i >> 7, d = i & 127;
    Ks[r][d] = QKV[(size_t)(kt * 64 + r) * N3 + KOFF + kvh * HD + d];
  }
  const int qr = tid >> 2;
  const int seg = tid & 3;
  const int c0 = seg * 16;
  float csum = 0.f;

  for (int qt = kt; qt < S / 64; ++qt) {
    __syncthreads();
    for (int i = tid; i < 64 * HD; i += 256) {
      int r = i >> 7, d = i & 127;
      Qs[r][d] = QKV[(size_t)(qt * 64 + r) * N3 + h * HD + d];
    }
    if (tid < 64) {
      mq[tid] = mbuf[h * S + qt * 64 + tid];
      linv[tid] = 1.0f / lbuf[h * S + qt * 64 + tid];
    }
    __syncthreads();
    float acc[16];
#pragma unroll
    for (int c = 0; c < 16; ++c) acc[c] = 0.f;
    for (int d = 0; d < HD; ++d) {
      float qv = Qs[qr][d];
#pragma unroll
      for (int c = 0; c < 16; ++c) acc[c] += qv * Ks[c0 + c][d];
    }
    const int qg = qt * 64 + qr;
#pragma unroll
    for (int c = 0; c < 16; ++c) {
      int kg = kt * 64 + c0 + c;
      Ps[qr][c0 + c] =
          (kg <= qg) ? __expf(acc[c] * SCALE - mq[qr]) * linv[qr] : 0.f;
    }
    __syncthreads();
    if (tid < 64) {
      float s = 0.f;
      for (int r = 0; r < 64; ++r) s += Ps[r][tid];
      csum += s;
    }
    __syncthreads();
  }
  if (tid < 64) {
    int kg = kt * 64 + tid;
    if (kg < S) cur[h * S + kg] = csum;
  }
}

// ---------------------------------------------------------------------------
// top-k + mask (unchanged)
// ---------------------------------------------------------------------------
__global__ __launch_bounds__(256) void topk_kernel(
    const float* __restrict__ cur, float* __restrict__ mask) {
  const int h = blockIdx.x;
  const int tid = threadIdx.x;
  __shared__ unsigned uv[SKEEP];
  __shared__ int red[256];

  for (int i = tid; i < SKEEP; i += 256) uv[i] = __float_as_uint(cur[h * S + i]);
  __syncthreads();

  unsigned lo = 0u, hi = 0xffffffffu;
  while (lo < hi) {
    unsigned mid = (unsigned)((((unsigned long long)lo + hi) + 1ull) >> 1);
    int c = 0;
    for (int i = tid; i < SKEEP; i += 256) c += (uv[i] >= mid) ? 1 : 0;
    red[tid] = c;
    __syncthreads();
    for (int s = 128; s > 0; s >>= 1) {
      if (tid < s) red[tid] += red[tid + s];
      __syncthreads();
    }
    int cnt = red[0];
    __syncthreads();
    if (cnt >= HEAVY) lo = mid; else hi = mid - 1;
  }
  const unsigned vk = lo;
  int c = 0;
  for (int i = tid; i < SKEEP; i += 256) c += (uv[i] > vk) ? 1 : 0;
  red[tid] = c;
  __syncthreads();
  for (int s = 128; s > 0; s >>= 1) {
    if (tid < s) red[tid] += red[tid + s];
    __syncthreads();
  }
  const int cgt = red[0];
  __syncthreads();
  const int r = HEAVY - cgt;

  for (int j = tid; j < MASKC; j += 256)
    mask[(size_t)h * MASKC + j] = (j >= MASKC - RECENT) ? 1.0f : 0.0f;
  __syncthreads();
  for (int i = tid; i < SKEEP; i += 256)
    if (uv[i] > vk) mask[(size_t)h * MASKC + i] = 1.0f;
  if (tid == 0) {
    int rem = r;
    for (int i = 0; i < SKEEP && rem > 0; ++i) {
      if (uv[i] == vk) { mask[(size_t)h * MASKC + i] = 1.0f; --rem; }
    }
  }
}

// ---------------------------------------------------------------------------
extern "C" void kernel_launch(void* const* d_in, const int* in_sizes, int n_in,
                              void* d_out, int out_size, void* d_ws,
                              size_t ws_size, hipStream_t stream) {
  const float* hs  = (const float*)d_in[0];
  const float* q_w = (const float*)d_in[1];
  const float* q_b = (const float*)d_in[2];
  const float* k_w = (const float*)d_in[3];
  const float* k_b = (const float*)d_in[4];
  const float* v_w = (const float*)d_in[5];
  const float* v_b = (const float*)d_in[6];
  const float* o_w = (const float*)d_in[7];

  char* ws = (char*)d_ws;
  // fp32 buffers
  float* QKV  = (float*)ws;                              // 2048*3072*4 = 25165824
  float* AO   = (float*)(ws + 25165824);                 // 2048*2048*4 = 16777216
  float* mb   = (float*)(ws + 41943040);                 // 16*2048*4 = 131072
  float* lb   = (float*)(ws + 42074112);
  float* cur  = (float*)(ws + 42205184);
  float* bcat = (float*)(ws + 42336256);                 // 3072*4
  // bf16 pool (reused for oproj stage)
  char* pool = ws + 42348544;
  unsigned short* hsh = (unsigned short*)pool;                      // 8388608 B
  unsigned short* hsl = (unsigned short*)(pool + 8388608);          // 8388608 B
  unsigned short* WTh = (unsigned short*)(pool + 16777216);         // 3072*2048*2 = 12582912
  unsigned short* WTl = (unsigned short*)(pool + 16777216 + 12582912);
  // aliases for oproj stage (after attn, hs/WT no longer needed)
  unsigned short* AOh = hsh;
  unsigned short* AOl = hsl;
  unsigned short* OTh = WTh;
  unsigned short* OTl = WTl;

  float* outp  = (float*)d_out;
  float* maskp = outp + (size_t)S * D;

  dim3 blk(256);
  // 1. split hidden states
  split_act<<<dim3(2048), blk, 0, stream>>>(hs, hsh, hsl, S * D);
  // 2. split+transpose weights into fused [3072][2048]
  split_wT<<<dim3(NQ / 64, D / 64), blk, 0, stream>>>(q_w, WTh, WTl, D, NQ, 0, D);
  split_wT<<<dim3(NKV / 64, D / 64), blk, 0, stream>>>(k_w, WTh, WTl, D, NKV, KOFF, D);
  split_wT<<<dim3(NKV / 64, D / 64), blk, 0, stream>>>(v_w, WTh, WTl, D, NKV, VOFF, D);
  concat_bias<<<dim3((N3 + 255) / 256), blk, 0, stream>>>(q_b, k_b, v_b, bcat);
  // 3. fused QKV projection (split-bf16 MFMA)
  gemm_split<<<dim3(N3 / 128, S / 128), blk, 0, stream>>>(
      hsh, hsl, WTh, WTl, bcat, QKV, S, N3, D);
  // 4. attention
  attn_kernel<<<dim3(S / 64, H), blk, 0, stream>>>(QKV, AO, mb, lb);
  // 5. cur scores + topk mask
  cur_kernel<<<dim3((SKEEP + 63) / 64, H), blk, 0, stream>>>(QKV, mb, lb, cur);
  topk_kernel<<<dim3(H), blk, 0, stream>>>(cur, maskp);
  // 6. output projection (split-bf16 MFMA, no bias)
  split_act<<<dim3(2048), blk, 0, stream>>>(AO, AOh, AOl, S * NQ);
  split_wT<<<dim3(D / 64, NQ / 64), blk, 0, stream>>>(o_w, OTh, OTl, NQ, D, 0, NQ);
  gemm_split<<<dim3(D / 128, S / 128), blk, 0, stream>>>(
      AOh, AOl, OTh, OTl, nullptr, outp, S, D, NQ);
}

// Round 4
// 566.406 us; speedup vs baseline: 9.5113x; 7.3118x over previous
//
#include <hip/hip_runtime.h>
#include <hip/hip_bf16.h>
#include <math.h>

// Problem constants
constexpr int S   = 2048;
constexpr int D   = 2048;
constexpr int H   = 16;
constexpr int KVH = 4;
constexpr int HD  = 128;
constexpr int NQ  = H * HD;      // 2048
constexpr int NKV = KVH * HD;    // 512
constexpr int N3  = NQ + 2 * NKV; // 3072 fused QKV columns
constexpr int KOFF = NQ;          // 2048
constexpr int VOFF = NQ + NKV;    // 2560
constexpr int GROUPS = H / KVH;   // 4
constexpr float SCALE = 0.088388347648318447f; // 128^-0.5
constexpr int HEAVY  = 204;
constexpr int RECENT = 204;
constexpr int SKEEP  = S - RECENT;  // 1844
constexpr int MASKC  = S + 1;       // 2049

typedef short bf16x8 __attribute__((ext_vector_type(8)));
typedef unsigned short ushort8 __attribute__((ext_vector_type(8)));
typedef float f32x4 __attribute__((ext_vector_type(4)));

__device__ __forceinline__ unsigned short f2b(float x) {
  __hip_bfloat16 h = __float2bfloat16(x);
  return *(unsigned short*)&h;
}
__device__ __forceinline__ float b2f(unsigned short u) {
  __hip_bfloat16 h = *(__hip_bfloat16*)&u;
  return __bfloat162float(h);
}

// ---------------------------------------------------------------------------
// split_act: fp32 [n] -> bf16 hi/lo pair
// ---------------------------------------------------------------------------
__global__ __launch_bounds__(256) void split_act(
    const float* __restrict__ in, unsigned short* __restrict__ oh,
    unsigned short* __restrict__ ol, int n) {
  for (int i = blockIdx.x * 256 + threadIdx.x; i < n; i += gridDim.x * 256) {
    float x = in[i];
    unsigned short h = f2b(x);
    float rem = x - b2f(h);
    oh[i] = h;
    ol[i] = f2b(rem);
  }
}

// ---------------------------------------------------------------------------
// split_wT: in[K][N] fp32 -> out[rowOff + n][k] bf16 hi/lo (transposed split)
// ---------------------------------------------------------------------------
__global__ __launch_bounds__(256) void split_wT(
    const float* __restrict__ in, unsigned short* __restrict__ oh,
    unsigned short* __restrict__ ol, int K, int N, int rowOff, int ldOut) {
  __shared__ float Lt[64][65];
  const int n0 = blockIdx.x * 64, k0 = blockIdx.y * 64;
  const int t = threadIdx.x;
  const int cq = t & 15, r4 = t >> 4;
#pragma unroll
  for (int i = 0; i < 4; ++i) {
    int r = r4 + i * 16;  // k row
    float4 v = *(const float4*)&in[(size_t)(k0 + r) * N + n0 + cq * 4];
    Lt[cq * 4 + 0][r] = v.x;
    Lt[cq * 4 + 1][r] = v.y;
    Lt[cq * 4 + 2][r] = v.z;
    Lt[cq * 4 + 3][r] = v.w;
  }
  __syncthreads();
#pragma unroll
  for (int i = 0; i < 4; ++i) {
    int rr = r4 + i * 16;  // n row of output
    size_t base = (size_t)(rowOff + n0 + rr) * ldOut + k0 + cq * 4;
#pragma unroll
    for (int j = 0; j < 4; ++j) {
      float x = Lt[rr][cq * 4 + j];
      unsigned short h = f2b(x);
      oh[base + j] = h;
      ol[base + j] = f2b(x - b2f(h));
    }
  }
}

// ---------------------------------------------------------------------------
// concat_bias
// ---------------------------------------------------------------------------
__global__ void concat_bias(const float* qb, const float* kb, const float* vb,
                            float* out) {
  int i = blockIdx.x * 256 + threadIdx.x;
  if (i < NQ) out[i] = qb[i];
  else if (i < VOFF) out[i] = kb[i - KOFF];
  else if (i < N3) out[i] = vb[i - VOFF];
}

// ---------------------------------------------------------------------------
// Split-bf16 MFMA GEMM (unchanged from R3, verified)
// ---------------------------------------------------------------------------
__global__ __launch_bounds__(256) void gemm_split(
    const unsigned short* __restrict__ Ah, const unsigned short* __restrict__ Al,
    const unsigned short* __restrict__ Bh, const unsigned short* __restrict__ Bl,
    const float* __restrict__ bias, float* __restrict__ C,
    int M, int N, int K) {
  __shared__ __align__(16) unsigned short sAh[128 * 40];
  __shared__ __align__(16) unsigned short sAl[128 * 40];
  __shared__ __align__(16) unsigned short sBh[128 * 40];
  __shared__ __align__(16) unsigned short sBl[128 * 40];
  const int tid = threadIdx.x;
  const int lane = tid & 63, wave = tid >> 6;
  const int wm = wave >> 1, wn = wave & 1;
  const int quad = lane >> 4, l16 = lane & 15;
  const int m0 = blockIdx.y * 128, n0 = blockIdx.x * 128;

  f32x4 acc[4][4];
#pragma unroll
  for (int i = 0; i < 4; ++i)
#pragma unroll
    for (int j = 0; j < 4; ++j) acc[i][j] = (f32x4){0.f, 0.f, 0.f, 0.f};

  for (int k0 = 0; k0 < K; k0 += 32) {
#pragma unroll
    for (int it = 0; it < 2; ++it) {
      int c = tid + it * 256;
      int r = c >> 2, sub = c & 3;
      size_t ga = (size_t)(m0 + r) * K + k0 + sub * 8;
      size_t gb = (size_t)(n0 + r) * K + k0 + sub * 8;
      int li = r * 40 + sub * 8;
      *(ushort8*)&sAh[li] = *(const ushort8*)&Ah[ga];
      *(ushort8*)&sAl[li] = *(const ushort8*)&Al[ga];
      *(ushort8*)&sBh[li] = *(const ushort8*)&Bh[gb];
      *(ushort8*)&sBl[li] = *(const ushort8*)&Bl[gb];
    }
    __syncthreads();
    bf16x8 fah[4], fal[4], fbh[4], fbl[4];
#pragma unroll
    for (int i = 0; i < 4; ++i) {
      int ra = (wm * 64 + i * 16 + l16) * 40 + quad * 8;
      fah[i] = *(bf16x8*)&sAh[ra];
      fal[i] = *(bf16x8*)&sAl[ra];
      int rb = (wn * 64 + i * 16 + l16) * 40 + quad * 8;
      fbh[i] = *(bf16x8*)&sBh[rb];
      fbl[i] = *(bf16x8*)&sBl[rb];
    }
#pragma unroll
    for (int i = 0; i < 4; ++i)
#pragma unroll
      for (int j = 0; j < 4; ++j) {
        acc[i][j] = __builtin_amdgcn_mfma_f32_16x16x32_bf16(fah[i], fbh[j], acc[i][j], 0, 0, 0);
        acc[i][j] = __builtin_amdgcn_mfma_f32_16x16x32_bf16(fah[i], fbl[j], acc[i][j], 0, 0, 0);
        acc[i][j] = __builtin_amdgcn_mfma_f32_16x16x32_bf16(fal[i], fbh[j], acc[i][j], 0, 0, 0);
      }
    __syncthreads();
  }
#pragma unroll
  for (int i = 0; i < 4; ++i) {
#pragma unroll
    for (int j = 0; j < 4; ++j) {
      int row = m0 + wm * 64 + i * 16 + quad * 4;
      int col = n0 + wn * 64 + j * 16 + l16;
      float bv = bias ? bias[col] : 0.0f;
#pragma unroll
      for (int r = 0; r < 4; ++r) {
        C[(size_t)(row + r) * N + col] = acc[i][j][r] + bv;
      }
    }
  }
}

// ---------------------------------------------------------------------------
// prep_q: QKV[s][0..2047] -> Qh/Ql [S][NQ] bf16
// ---------------------------------------------------------------------------
__global__ __launch_bounds__(256) void prep_q(
    const float* __restrict__ QKV, unsigned short* __restrict__ Qh,
    unsigned short* __restrict__ Ql) {
  const int s = blockIdx.x;
  for (int c = threadIdx.x; c < NQ; c += 256) {
    float x = QKV[(size_t)s * N3 + c];
    unsigned short h = f2b(x);
    Qh[(size_t)s * NQ + c] = h;
    Ql[(size_t)s * NQ + c] = f2b(x - b2f(h));
  }
}

// ---------------------------------------------------------------------------
// prep_k: QKV[s][KOFF + kvh*128 + d] -> Kh/Kl [kvh][S][HD] bf16
// ---------------------------------------------------------------------------
__global__ __launch_bounds__(256) void prep_k(
    const float* __restrict__ QKV, unsigned short* __restrict__ Kh,
    unsigned short* __restrict__ Kl) {
  const int s = blockIdx.x;
  for (int c = threadIdx.x; c < NKV; c += 256) {
    int kvh = c >> 7, d = c & 127;
    float x = QKV[(size_t)s * N3 + KOFF + c];
    size_t o = ((size_t)kvh * S + s) * HD + d;
    unsigned short h = f2b(x);
    Kh[o] = h;
    Kl[o] = f2b(x - b2f(h));
  }
}

// ---------------------------------------------------------------------------
// prep_vt: QKV V part -> Vt [kvh][HD][S] bf16 (transposed), LDS tile
// grid (S/64, KVH)
// ---------------------------------------------------------------------------
__global__ __launch_bounds__(256) void prep_vt(
    const float* __restrict__ QKV, unsigned short* __restrict__ Vt) {
  __shared__ float Lt[128][73];
  const int s0 = blockIdx.x * 64, kvh = blockIdx.y;
  const int tid = threadIdx.x;
  for (int it = 0; it < 32; ++it) {
    int idx = tid + it * 256;        // 0..8191 = 64 s x 128 d
    int sl = idx >> 7, d = idx & 127;
    Lt[d][sl] = QKV[(size_t)(s0 + sl) * N3 + VOFF + kvh * HD + d];
  }
  __syncthreads();
  for (int it = 0; it < 32; ++it) {
    int idx = tid + it * 256;        // 128 d x 64 s
    int d = idx >> 6, sl = idx & 63;
    Vt[((size_t)kvh * HD + d) * S + s0 + sl] = f2b(Lt[d][sl]);
  }
}

// ---------------------------------------------------------------------------
// MFMA flash attention. Block = (64 q-rows, head); 4 waves x 16 q-rows.
// Split-bf16 QK^T (3 MFMAs) for accurate m/l; bf16 P,V for PV.
// ---------------------------------------------------------------------------
__global__ __launch_bounds__(256) void attn_mfma(
    const unsigned short* __restrict__ Qh, const unsigned short* __restrict__ Ql,
    const unsigned short* __restrict__ Kh, const unsigned short* __restrict__ Kl,
    const unsigned short* __restrict__ Vt, float* __restrict__ AO,
    float* __restrict__ mbuf, float* __restrict__ lbuf) {
  const int qt = blockIdx.x, h = blockIdx.y;
  const int kvh = h / GROUPS;
  const int tid = threadIdx.x;
  const int lane = tid & 63, w = tid >> 6;
  const int quad = lane >> 4, l16 = lane & 15;
  const int q0 = qt * 64;

  __shared__ __align__(16) unsigned short smem[31232];  // 62464 B
  unsigned short* sQh = smem;             // 8704 shorts (phase 1)
  unsigned short* sQl = smem + 8704;
  unsigned short* sKh = smem;             // phase 2 reuse
  unsigned short* sKl = smem + 8704;
  unsigned short* sVt = smem + 17408;     // 128 x 72
  unsigned short* sP  = smem + 26624;     // 4 waves x 16 x 72

  // ---- stage Q tile, load A-frags to registers ----
#pragma unroll
  for (int it = 0; it < 4; ++it) {
    int idx = tid + it * 256;  // 1024 chunks: 64 rows x 16
    int r = idx >> 4, c8 = idx & 15;
    size_t g = (size_t)(q0 + r) * NQ + h * HD + c8 * 8;
    int li = r * 136 + c8 * 8;
    *(ushort8*)&sQh[li] = *(const ushort8*)&Qh[g];
    *(ushort8*)&sQl[li] = *(const ushort8*)&Ql[g];
  }
  __syncthreads();
  bf16x8 fqh[4], fql[4];
#pragma unroll
  for (int d4 = 0; d4 < 4; ++d4) {
    int a = (w * 16 + l16) * 136 + d4 * 32 + quad * 8;
    fqh[d4] = *(bf16x8*)&sQh[a];
    fql[d4] = *(bf16x8*)&sQl[a];
  }
  __syncthreads();

  f32x4 O[8];
#pragma unroll
  for (int jn = 0; jn < 8; ++jn) O[jn] = (f32x4){0.f, 0.f, 0.f, 0.f};
  float m_[4], l_[4];
#pragma unroll
  for (int r = 0; r < 4; ++r) { m_[r] = -INFINITY; l_[r] = 0.f; }

  const int row_l = w * 16 + quad * 4;  // + r
  const int wbase = w * 1152;           // 16*72

  for (int kt = 0; kt <= qt; ++kt) {
    // stage K (hi/lo) + Vt tile
#pragma unroll
    for (int it = 0; it < 4; ++it) {
      int idx = tid + it * 256;
      int r = idx >> 4, c8 = idx & 15;
      size_t g = ((size_t)kvh * S + kt * 64 + r) * HD + c8 * 8;
      int li = r * 136 + c8 * 8;
      *(ushort8*)&sKh[li] = *(const ushort8*)&Kh[g];
      *(ushort8*)&sKl[li] = *(const ushort8*)&Kl[g];
    }
#pragma unroll
    for (int it = 0; it < 4; ++it) {
      int idx = tid + it * 256;  // 128 d x 8 chunks
      int d = idx >> 3, c8 = idx & 7;
      size_t g = ((size_t)kvh * HD + d) * S + kt * 64 + c8 * 8;
      *(ushort8*)&sVt[d * 72 + c8 * 8] = *(const ushort8*)&Vt[g];
    }
    __syncthreads();

    // S = Q K^T (split 3-term)
    f32x4 sc[4];
#pragma unroll
    for (int j = 0; j < 4; ++j) sc[j] = (f32x4){0.f, 0.f, 0.f, 0.f};
#pragma unroll
    for (int d4 = 0; d4 < 4; ++d4) {
#pragma unroll
      for (int j = 0; j < 4; ++j) {
        int b = (j * 16 + l16) * 136 + d4 * 32 + quad * 8;
        bf16x8 bh = *(bf16x8*)&sKh[b];
        bf16x8 bl = *(bf16x8*)&sKl[b];
        sc[j] = __builtin_amdgcn_mfma_f32_16x16x32_bf16(fqh[d4], bh, sc[j], 0, 0, 0);
        sc[j] = __builtin_amdgcn_mfma_f32_16x16x32_bf16(fqh[d4], bl, sc[j], 0, 0, 0);
        sc[j] = __builtin_amdgcn_mfma_f32_16x16x32_bf16(fql[d4], bh, sc[j], 0, 0, 0);
      }
    }
    // scale + causal mask (diag tile only)
    const bool diag = (kt == qt);
#pragma unroll
    for (int j = 0; j < 4; ++j) {
      int col_l = j * 16 + l16;
#pragma unroll
      for (int r = 0; r < 4; ++r) {
        float v = sc[j][r] * SCALE;
        if (diag && col_l > row_l + r) v = -INFINITY;
        sc[j][r] = v;
      }
    }
    // row max (over j, then 16 lanes)
    float tm[4];
#pragma unroll
    for (int r = 0; r < 4; ++r) {
      float t = sc[0][r];
#pragma unroll
      for (int j = 1; j < 4; ++j) t = fmaxf(t, sc[j][r]);
      tm[r] = t;
    }
#pragma unroll
    for (int off = 1; off < 16; off <<= 1)
#pragma unroll
      for (int r = 0; r < 4; ++r) tm[r] = fmaxf(tm[r], __shfl_xor(tm[r], off));
    // online softmax update
    float alpha[4];
#pragma unroll
    for (int r = 0; r < 4; ++r) {
      float mn = fmaxf(m_[r], tm[r]);
      alpha[r] = __expf(m_[r] - mn);
      m_[r] = mn;
    }
    float psum[4] = {0.f, 0.f, 0.f, 0.f};
#pragma unroll
    for (int j = 0; j < 4; ++j)
#pragma unroll
      for (int r = 0; r < 4; ++r) {
        float p = __expf(sc[j][r] - m_[r]);
        sc[j][r] = p;
        psum[r] += p;
      }
#pragma unroll
    for (int off = 1; off < 16; off <<= 1)
#pragma unroll
      for (int r = 0; r < 4; ++r) psum[r] += __shfl_xor(psum[r], off);
#pragma unroll
    for (int r = 0; r < 4; ++r) l_[r] = l_[r] * alpha[r] + psum[r];
    // rescale O, round-trip P through per-wave LDS region
#pragma unroll
    for (int jn = 0; jn < 8; ++jn)
#pragma unroll
      for (int r = 0; r < 4; ++r) O[jn][r] *= alpha[r];
#pragma unroll
    for (int j = 0; j < 4; ++j)
#pragma unroll
      for (int r = 0; r < 4; ++r)
        sP[wbase + (quad * 4 + r) * 72 + j * 16 + l16] = f2b(sc[j][r]);
    bf16x8 ap0 = *(bf16x8*)&sP[wbase + l16 * 72 + quad * 8];
    bf16x8 ap1 = *(bf16x8*)&sP[wbase + l16 * 72 + 32 + quad * 8];
    // PV
#pragma unroll
    for (int jn = 0; jn < 8; ++jn) {
      bf16x8 bv0 = *(bf16x8*)&sVt[(jn * 16 + l16) * 72 + quad * 8];
      bf16x8 bv1 = *(bf16x8*)&sVt[(jn * 16 + l16) * 72 + 32 + quad * 8];
      O[jn] = __builtin_amdgcn_mfma_f32_16x16x32_bf16(ap0, bv0, O[jn], 0, 0, 0);
      O[jn] = __builtin_amdgcn_mfma_f32_16x16x32_bf16(ap1, bv1, O[jn], 0, 0, 0);
    }
    __syncthreads();
  }
  // epilogue
  float linv[4];
#pragma unroll
  for (int r = 0; r < 4; ++r) linv[r] = 1.0f / l_[r];
#pragma unroll
  for (int jn = 0; jn < 8; ++jn)
#pragma unroll
    for (int r = 0; r < 4; ++r)
      AO[(size_t)(q0 + row_l + r) * NQ + h * HD + jn * 16 + l16] =
          O[jn][r] * linv[r];
  if (l16 == 0) {
#pragma unroll
    for (int r = 0; r < 4; ++r) {
      mbuf[h * S + q0 + row_l + r] = m_[r];
      lbuf[h * S + q0 + row_l + r] = l_[r];
    }
  }
}

// ---------------------------------------------------------------------------
// MFMA cur pass. Block = (64 k-cols, head). A = K rows (regs), loop q-tiles.
// cur[h][k] = sum_q exp(s*SCALE - m_q)/l_q (fp32 accumulation).
// ---------------------------------------------------------------------------
__global__ __launch_bounds__(256) void cur_mfma(
    const unsigned short* __restrict__ Qh, const unsigned short* __restrict__ Ql,
    const unsigned short* __restrict__ Kh, const unsigned short* __restrict__ Kl,
    const float* __restrict__ mbuf, const float* __restrict__ lbuf,
    float* __restrict__ cur) {
  const int kt = blockIdx.x, h = blockIdx.y;
  const int kvh = h / GROUPS;
  const int tid = threadIdx.x;
  const int lane = tid & 63, w = tid >> 6;
  const int quad = lane >> 4, l16 = lane & 15;

  __shared__ __align__(16) unsigned short sKh[8704];
  __shared__ __align__(16) unsigned short sKl[8704];
  __shared__ __align__(16) unsigned short sQh[8704];
  __shared__ __align__(16) unsigned short sQl[8704];
  __shared__ float smq[64], slinv[64];

  // stage K tile once
#pragma unroll
  for (int it = 0; it < 4; ++it) {
    int idx = tid + it * 256;
    int r = idx >> 4, c8 = idx & 15;
    size_t g = ((size_t)kvh * S + kt * 64 + r) * HD + c8 * 8;
    int li = r * 136 + c8 * 8;
    *(ushort8*)&sKh[li] = *(const ushort8*)&Kh[g];
    *(ushort8*)&sKl[li] = *(const ushort8*)&Kl[g];
  }
  __syncthreads();
  bf16x8 fkh[4], fkl[4];
#pragma unroll
  for (int d4 = 0; d4 < 4; ++d4) {
    int a = (w * 16 + l16) * 136 + d4 * 32 + quad * 8;
    fkh[d4] = *(bf16x8*)&sKh[a];
    fkl[d4] = *(bf16x8*)&sKl[a];
  }

  const int krow_l = w * 16 + quad * 4;  // + r
  float csum[4] = {0.f, 0.f, 0.f, 0.f};

  for (int qt = kt; qt < S / 64; ++qt) {
    __syncthreads();  // protect prior iteration's sQh reads
#pragma unroll
    for (int it = 0; it < 4; ++it) {
      int idx = tid + it * 256;
      int r = idx >> 4, c8 = idx & 15;
      size_t g = (size_t)(qt * 64 + r) * NQ + h * HD + c8 * 8;
      int li = r * 136 + c8 * 8;
      *(ushort8*)&sQh[li] = *(const ushort8*)&Qh[g];
      *(ushort8*)&sQl[li] = *(const ushort8*)&Ql[g];
    }
    if (tid < 64) {
      smq[tid] = mbuf[h * S + qt * 64 + tid];
      slinv[tid] = 1.0f / lbuf[h * S + qt * 64 + tid];
    }
    __syncthreads();
    f32x4 sc[4];
#pragma unroll
    for (int j = 0; j < 4; ++j) sc[j] = (f32x4){0.f, 0.f, 0.f, 0.f};
#pragma unroll
    for (int d4 = 0; d4 < 4; ++d4) {
#pragma unroll
      for (int j = 0; j < 4; ++j) {
        int b = (j * 16 + l16) * 136 + d4 * 32 + quad * 8;
        bf16x8 bh = *(bf16x8*)&sQh[b];
        bf16x8 bl = *(bf16x8*)&sQl[b];
        sc[j] = __builtin_amdgcn_mfma_f32_16x16x32_bf16(fkh[d4], bh, sc[j], 0, 0, 0);
        sc[j] = __builtin_amdgcn_mfma_f32_16x16x32_bf16(fkh[d4], bl, sc[j], 0, 0, 0);
        sc[j] = __builtin_amdgcn_mfma_f32_16x16x32_bf16(fkl[d4], bh, sc[j], 0, 0, 0);
      }
    }
    const bool diag = (qt == kt);
#pragma unroll
    for (int j = 0; j < 4; ++j) {
      int qcol_l = j * 16 + l16;
      float mqv = smq[qcol_l];
      float lv = slinv[qcol_l];
#pragma unroll
      for (int r = 0; r < 4; ++r) {
        float p = __expf(sc[j][r] * SCALE - mqv) * lv;
        if (diag && (krow_l + r) > qcol_l) p = 0.f;
        csum[r] += p;
      }
    }
  }
#pragma unroll
  for (int off = 1; off < 16; off <<= 1)
#pragma unroll
    for (int r = 0; r < 4; ++r) csum[r] += __shfl_xor(csum[r], off);
  if (l16 == 0) {
#pragma unroll
    for (int r = 0; r < 4; ++r)
      cur[h * S + kt * 64 + krow_l + r] = csum[r];
  }
}

// ---------------------------------------------------------------------------
// top-k + mask (unchanged, verified)
// ---------------------------------------------------------------------------
__global__ __launch_bounds__(256) void topk_kernel(
    const float* __restrict__ cur, float* __restrict__ mask) {
  const int h = blockIdx.x;
  const int tid = threadIdx.x;
  __shared__ unsigned uv[SKEEP];
  __shared__ int red[256];

  for (int i = tid; i < SKEEP; i += 256) uv[i] = __float_as_uint(cur[h * S + i]);
  __syncthreads();

  unsigned lo = 0u, hi = 0xffffffffu;
  while (lo < hi) {
    unsigned mid = (unsigned)((((unsigned long long)lo + hi) + 1ull) >> 1);
    int c = 0;
    for (int i = tid; i < SKEEP; i += 256) c += (uv[i] >= mid) ? 1 : 0;
    red[tid] = c;
    __syncthreads();
    for (int s = 128; s > 0; s >>= 1) {
      if (tid < s) red[tid] += red[tid + s];
      __syncthreads();
    }
    int cnt = red[0];
    __syncthreads();
    if (cnt >= HEAVY) lo = mid; else hi = mid - 1;
  }
  const unsigned vk = lo;
  int c = 0;
  for (int i = tid; i < SKEEP; i += 256) c += (uv[i] > vk) ? 1 : 0;
  red[tid] = c;
  __syncthreads();
  for (int s = 128; s > 0; s >>= 1) {
    if (tid < s) red[tid] += red[tid + s];
    __syncthreads();
  }
  const int cgt = red[0];
  __syncthreads();
  const int r = HEAVY - cgt;

  for (int j = tid; j < MASKC; j += 256)
    mask[(size_t)h * MASKC + j] = (j >= MASKC - RECENT) ? 1.0f : 0.0f;
  __syncthreads();
  for (int i = tid; i < SKEEP; i += 256)
    if (uv[i] > vk) mask[(size_t)h * MASKC + i] = 1.0f;
  if (tid == 0) {
    int rem = r;
    for (int i = 0; i < SKEEP && rem > 0; ++i) {
      if (uv[i] == vk) { mask[(size_t)h * MASKC + i] = 1.0f; --rem; }
    }
  }
}

// ---------------------------------------------------------------------------
extern "C" void kernel_launch(void* const* d_in, const int* in_sizes, int n_in,
                              void* d_out, int out_size, void* d_ws,
                              size_t ws_size, hipStream_t stream) {
  const float* hs  = (const float*)d_in[0];
  const float* q_w = (const float*)d_in[1];
  const float* q_b = (const float*)d_in[2];
  const float* k_w = (const float*)d_in[3];
  const float* k_b = (const float*)d_in[4];
  const float* v_w = (const float*)d_in[5];
  const float* v_b = (const float*)d_in[6];
  const float* o_w = (const float*)d_in[7];

  char* ws = (char*)d_ws;
  float* QKV  = (float*)ws;                              // 25165824 B
  float* AO   = (float*)(ws + 25165824);                 // 16777216 B
  float* mb   = (float*)(ws + 41943040);                 // 131072 B
  float* lb   = (float*)(ws + 42074112);
  float* cur  = (float*)(ws + 42205184);
  float* bcat = (float*)(ws + 42336256);                 // 12288 B
  char* pool = ws + 42348544;                            // 41.9 MB pool
  // phase A: QKV projection operands
  unsigned short* hsh = (unsigned short*)pool;
  unsigned short* hsl = (unsigned short*)(pool + 8388608);
  unsigned short* WTh = (unsigned short*)(pool + 16777216);
  unsigned short* WTl = (unsigned short*)(pool + 29360128);
  // phase B: attention bf16 buffers (pool reuse, after QKV gemm)
  unsigned short* Qh = (unsigned short*)pool;                  // 8388608
  unsigned short* Ql = (unsigned short*)(pool + 8388608);      // 8388608
  unsigned short* Kh = (unsigned short*)(pool + 16777216);     // 2097152
  unsigned short* Kl = (unsigned short*)(pool + 18874368);     // 2097152
  unsigned short* Vt = (unsigned short*)(pool + 20971520);     // 2097152
  // phase C: oproj operands (pool reuse, after cur/topk)
  unsigned short* AOh = (unsigned short*)pool;
  unsigned short* AOl = (unsigned short*)(pool + 8388608);
  unsigned short* OTh = (unsigned short*)(pool + 16777216);
  unsigned short* OTl = (unsigned short*)(pool + 29360128);

  float* outp  = (float*)d_out;
  float* maskp = outp + (size_t)S * D;

  dim3 blk(256);
  // 1. QKV projection (split-bf16 MFMA)
  split_act<<<dim3(2048), blk, 0, stream>>>(hs, hsh, hsl, S * D);
  split_wT<<<dim3(NQ / 64, D / 64), blk, 0, stream>>>(q_w, WTh, WTl, D, NQ, 0, D);
  split_wT<<<dim3(NKV / 64, D / 64), blk, 0, stream>>>(k_w, WTh, WTl, D, NKV, KOFF, D);
  split_wT<<<dim3(NKV / 64, D / 64), blk, 0, stream>>>(v_w, WTh, WTl, D, NKV, VOFF, D);
  concat_bias<<<dim3((N3 + 255) / 256), blk, 0, stream>>>(q_b, k_b, v_b, bcat);
  gemm_split<<<dim3(N3 / 128, S / 128), blk, 0, stream>>>(
      hsh, hsl, WTh, WTl, bcat, QKV, S, N3, D);
  // 2. prep bf16 attention operands
  prep_q<<<dim3(S), blk, 0, stream>>>(QKV, Qh, Ql);
  prep_k<<<dim3(S), blk, 0, stream>>>(QKV, Kh, Kl);
  prep_vt<<<dim3(S / 64, KVH), blk, 0, stream>>>(QKV, Vt);
  // 3. MFMA flash attention
  attn_mfma<<<dim3(S / 64, H), blk, 0, stream>>>(Qh, Ql, Kh, Kl, Vt, AO, mb, lb);
  // 4. cur scores + topk mask
  cur_mfma<<<dim3((SKEEP + 63) / 64, H), blk, 0, stream>>>(Qh, Ql, Kh, Kl, mb, lb, cur);
  topk_kernel<<<dim3(H), blk, 0, stream>>>(cur, maskp);
  // 5. output projection
  split_act<<<dim3(2048), blk, 0, stream>>>(AO, AOh, AOl, S * NQ);
  split_wT<<<dim3(D / 64, NQ / 64), blk, 0, stream>>>(o_w, OTh, OTl, NQ, D, 0, NQ);
  gemm_split<<<dim3(D / 128, S / 128), blk, 0, stream>>>(
      AOh, AOl, OTh, OTl, nullptr, outp, S, D, NQ);
}

// Round 5
// 508.502 us; speedup vs baseline: 10.5944x; 1.1139x over previous
//
#include <hip/hip_runtime.h>
#include <hip/hip_bf16.h>
#include <math.h>

// Problem constants
constexpr int S   = 2048;
constexpr int D   = 2048;
constexpr int H   = 16;
constexpr int KVH = 4;
constexpr int HD  = 128;
constexpr int NQ  = H * HD;      // 2048
constexpr int NKV = KVH * HD;    // 512
constexpr int N3  = NQ + 2 * NKV; // 3072
constexpr int GROUPS = H / KVH;   // 4
constexpr float SCALE = 0.088388347648318447f; // 128^-0.5
constexpr int HEAVY  = 204;
constexpr int RECENT = 204;
constexpr int SKEEP  = S - RECENT;  // 1844
constexpr int MASKC  = S + 1;       // 2049

typedef short bf16x8 __attribute__((ext_vector_type(8)));
typedef unsigned short ushort8 __attribute__((ext_vector_type(8)));
typedef float f32x4 __attribute__((ext_vector_type(4)));

__device__ __forceinline__ unsigned short f2b(float x) {
  __hip_bfloat16 h = __float2bfloat16(x);
  return *(unsigned short*)&h;
}
__device__ __forceinline__ float b2f(unsigned short u) {
  __hip_bfloat16 h = *(__hip_bfloat16*)&u;
  return __bfloat162float(h);
}

// ---------------------------------------------------------------------------
// split_act: fp32 [n] -> bf16 hi/lo pair (hidden states)
// ---------------------------------------------------------------------------
__global__ __launch_bounds__(256) void split_act(
    const float* __restrict__ in, unsigned short* __restrict__ oh,
    unsigned short* __restrict__ ol, int n) {
  for (int i = blockIdx.x * 256 + threadIdx.x; i < n; i += gridDim.x * 256) {
    float x = in[i];
    unsigned short h = f2b(x);
    oh[i] = h;
    ol[i] = f2b(x - b2f(h));
  }
}

// ---------------------------------------------------------------------------
// split_wT: in[K][N] fp32 -> out[rowOff + n][k] bf16 hi/lo (transposed split)
// ---------------------------------------------------------------------------
__global__ __launch_bounds__(256) void split_wT(
    const float* __restrict__ in, unsigned short* __restrict__ oh,
    unsigned short* __restrict__ ol, int K, int N, int rowOff, int ldOut) {
  __shared__ float Lt[64][65];
  const int n0 = blockIdx.x * 64, k0 = blockIdx.y * 64;
  const int t = threadIdx.x;
  const int cq = t & 15, r4 = t >> 4;
#pragma unroll
  for (int i = 0; i < 4; ++i) {
    int r = r4 + i * 16;
    float4 v = *(const float4*)&in[(size_t)(k0 + r) * N + n0 + cq * 4];
    Lt[cq * 4 + 0][r] = v.x;
    Lt[cq * 4 + 1][r] = v.y;
    Lt[cq * 4 + 2][r] = v.z;
    Lt[cq * 4 + 3][r] = v.w;
  }
  __syncthreads();
#pragma unroll
  for (int i = 0; i < 4; ++i) {
    int rr = r4 + i * 16;
    size_t base = (size_t)(rowOff + n0 + rr) * ldOut + k0 + cq * 4;
#pragma unroll
    for (int j = 0; j < 4; ++j) {
      float x = Lt[rr][cq * 4 + j];
      unsigned short h = f2b(x);
      oh[base + j] = h;
      ol[base + j] = f2b(x - b2f(h));
    }
  }
}

// ---------------------------------------------------------------------------
// wT_bf16: in[K][N] fp32 -> out[n][k] bf16 (hi only) — for o_w
// ---------------------------------------------------------------------------
__global__ __launch_bounds__(256) void wT_bf16(
    const float* __restrict__ in, unsigned short* __restrict__ oh,
    int K, int N) {
  __shared__ float Lt[64][65];
  const int n0 = blockIdx.x * 64, k0 = blockIdx.y * 64;
  const int t = threadIdx.x;
  const int cq = t & 15, r4 = t >> 4;
#pragma unroll
  for (int i = 0; i < 4; ++i) {
    int r = r4 + i * 16;
    float4 v = *(const float4*)&in[(size_t)(k0 + r) * N + n0 + cq * 4];
    Lt[cq * 4 + 0][r] = v.x;
    Lt[cq * 4 + 1][r] = v.y;
    Lt[cq * 4 + 2][r] = v.z;
    Lt[cq * 4 + 3][r] = v.w;
  }
  __syncthreads();
#pragma unroll
  for (int i = 0; i < 4; ++i) {
    int rr = r4 + i * 16;
    size_t base = (size_t)(n0 + rr) * K + k0 + cq * 4;
#pragma unroll
    for (int j = 0; j < 4; ++j) oh[base + j] = f2b(Lt[rr][cq * 4 + j]);
  }
}

// ---------------------------------------------------------------------------
// concat_bias
// ---------------------------------------------------------------------------
__global__ void concat_bias(const float* qb, const float* kb, const float* vb,
                            float* out) {
  int i = blockIdx.x * 256 + threadIdx.x;
  if (i < NQ) out[i] = qb[i];
  else if (i < NQ + NKV) out[i] = kb[i - NQ];
  else if (i < N3) out[i] = vb[i - NQ - NKV];
}

// ---------------------------------------------------------------------------
// QKV GEMM (split-bf16, 3 MFMA) with fused epilogue: writes Qh/Ql, Kh/Kl
// ([kvh][S][HD]) and Vrow bf16 directly. Each 128-col block is entirely
// within the Q, K, or V region (boundaries at 2048/2560 are multiples of 128).
// ---------------------------------------------------------------------------
__global__ __launch_bounds__(256) void gemm_qkv(
    const unsigned short* __restrict__ Ah, const unsigned short* __restrict__ Al,
    const unsigned short* __restrict__ Bh, const unsigned short* __restrict__ Bl,
    const float* __restrict__ bias,
    unsigned short* __restrict__ Qh, unsigned short* __restrict__ Ql,
    unsigned short* __restrict__ Kh, unsigned short* __restrict__ Kl,
    unsigned short* __restrict__ Vrow, int M, int N, int K) {
  __shared__ __align__(16) unsigned short sAh[128 * 40];
  __shared__ __align__(16) unsigned short sAl[128 * 40];
  __shared__ __align__(16) unsigned short sBh[128 * 40];
  __shared__ __align__(16) unsigned short sBl[128 * 40];
  const int tid = threadIdx.x;
  const int lane = tid & 63, wave = tid >> 6;
  const int wm = wave >> 1, wn = wave & 1;
  const int quad = lane >> 4, l16 = lane & 15;
  const int m0 = blockIdx.y * 128, n0 = blockIdx.x * 128;

  f32x4 acc[4][4];
#pragma unroll
  for (int i = 0; i < 4; ++i)
#pragma unroll
    for (int j = 0; j < 4; ++j) acc[i][j] = (f32x4){0.f, 0.f, 0.f, 0.f};

  for (int k0 = 0; k0 < K; k0 += 32) {
#pragma unroll
    for (int it = 0; it < 2; ++it) {
      int c = tid + it * 256;
      int r = c >> 2, sub = c & 3;
      size_t ga = (size_t)(m0 + r) * K + k0 + sub * 8;
      size_t gb = (size_t)(n0 + r) * K + k0 + sub * 8;
      int li = r * 40 + sub * 8;
      *(ushort8*)&sAh[li] = *(const ushort8*)&Ah[ga];
      *(ushort8*)&sAl[li] = *(const ushort8*)&Al[ga];
      *(ushort8*)&sBh[li] = *(const ushort8*)&Bh[gb];
      *(ushort8*)&sBl[li] = *(const ushort8*)&Bl[gb];
    }
    __syncthreads();
    bf16x8 fah[4], fal[4], fbh[4], fbl[4];
#pragma unroll
    for (int i = 0; i < 4; ++i) {
      int ra = (wm * 64 + i * 16 + l16) * 40 + quad * 8;
      fah[i] = *(bf16x8*)&sAh[ra];
      fal[i] = *(bf16x8*)&sAl[ra];
      int rb = (wn * 64 + i * 16 + l16) * 40 + quad * 8;
      fbh[i] = *(bf16x8*)&sBh[rb];
      fbl[i] = *(bf16x8*)&sBl[rb];
    }
#pragma unroll
    for (int i = 0; i < 4; ++i)
#pragma unroll
      for (int j = 0; j < 4; ++j) {
        acc[i][j] = __builtin_amdgcn_mfma_f32_16x16x32_bf16(fah[i], fbh[j], acc[i][j], 0, 0, 0);
        acc[i][j] = __builtin_amdgcn_mfma_f32_16x16x32_bf16(fah[i], fbl[j], acc[i][j], 0, 0, 0);
        acc[i][j] = __builtin_amdgcn_mfma_f32_16x16x32_bf16(fal[i], fbh[j], acc[i][j], 0, 0, 0);
      }
    __syncthreads();
  }
#pragma unroll
  for (int i = 0; i < 4; ++i) {
#pragma unroll
    for (int j = 0; j < 4; ++j) {
      int row = m0 + wm * 64 + i * 16 + quad * 4;
      int col = n0 + wn * 64 + j * 16 + l16;
      float bv = bias[col];
#pragma unroll
      for (int r = 0; r < 4; ++r) {
        float x = acc[i][j][r] + bv;
        unsigned short hb = f2b(x);
        unsigned short lb2 = f2b(x - b2f(hb));
        if (n0 < NQ) {
          size_t o = (size_t)(row + r) * NQ + col;
          Qh[o] = hb; Ql[o] = lb2;
        } else if (n0 < NQ + NKV) {
          int c = col - NQ;
          size_t o = ((size_t)(c >> 7) * S + row + r) * HD + (c & 127);
          Kh[o] = hb; Kl[o] = lb2;
        } else {
          int c = col - NQ - NKV;
          size_t o = ((size_t)(c >> 7) * S + row + r) * HD + (c & 127);
          Vrow[o] = hb;
        }
      }
    }
  }
}

// ---------------------------------------------------------------------------
// Plain bf16 GEMM for output projection: C fp32 = A[M][K] @ B^T[N][K]
// ---------------------------------------------------------------------------
__global__ __launch_bounds__(256) void gemm_bf16(
    const unsigned short* __restrict__ Ah, const unsigned short* __restrict__ Bh,
    float* __restrict__ C, int M, int N, int K) {
  __shared__ __align__(16) unsigned short sA[128 * 40];
  __shared__ __align__(16) unsigned short sB[128 * 40];
  const int tid = threadIdx.x;
  const int lane = tid & 63, wave = tid >> 6;
  const int wm = wave >> 1, wn = wave & 1;
  const int quad = lane >> 4, l16 = lane & 15;
  const int m0 = blockIdx.y * 128, n0 = blockIdx.x * 128;

  f32x4 acc[4][4];
#pragma unroll
  for (int i = 0; i < 4; ++i)
#pragma unroll
    for (int j = 0; j < 4; ++j) acc[i][j] = (f32x4){0.f, 0.f, 0.f, 0.f};

  for (int k0 = 0; k0 < K; k0 += 32) {
#pragma unroll
    for (int it = 0; it < 2; ++it) {
      int c = tid + it * 256;
      int r = c >> 2, sub = c & 3;
      size_t ga = (size_t)(m0 + r) * K + k0 + sub * 8;
      size_t gb = (size_t)(n0 + r) * K + k0 + sub * 8;
      int li = r * 40 + sub * 8;
      *(ushort8*)&sA[li] = *(const ushort8*)&Ah[ga];
      *(ushort8*)&sB[li] = *(const ushort8*)&Bh[gb];
    }
    __syncthreads();
    bf16x8 fa[4], fb[4];
#pragma unroll
    for (int i = 0; i < 4; ++i) {
      fa[i] = *(bf16x8*)&sA[(wm * 64 + i * 16 + l16) * 40 + quad * 8];
      fb[i] = *(bf16x8*)&sB[(wn * 64 + i * 16 + l16) * 40 + quad * 8];
    }
#pragma unroll
    for (int i = 0; i < 4; ++i)
#pragma unroll
      for (int j = 0; j < 4; ++j)
        acc[i][j] = __builtin_amdgcn_mfma_f32_16x16x32_bf16(fa[i], fb[j], acc[i][j], 0, 0, 0);
    __syncthreads();
  }
#pragma unroll
  for (int i = 0; i < 4; ++i)
#pragma unroll
    for (int j = 0; j < 4; ++j) {
      int row = m0 + wm * 64 + i * 16 + quad * 4;
      int col = n0 + wn * 64 + j * 16 + l16;
#pragma unroll
      for (int r = 0; r < 4; ++r)
        C[(size_t)(row + r) * N + col] = acc[i][j][r];
    }
}

// ---------------------------------------------------------------------------
// prep_vt: Vrow bf16 [kvh][s][d] -> Vt bf16 [kvh][d][S]
// ---------------------------------------------------------------------------
__global__ __launch_bounds__(256) void prep_vt(
    const unsigned short* __restrict__ Vrow, unsigned short* __restrict__ Vt) {
  __shared__ unsigned short Lt[128][66];
  const int s0 = blockIdx.x * 64, kvh = blockIdx.y;
  const int tid = threadIdx.x;
  for (int it = 0; it < 32; ++it) {
    int idx = tid + it * 256;  // 64 s x 128 d
    int sl = idx >> 7, d = idx & 127;
    Lt[d][sl] = Vrow[((size_t)kvh * S + s0 + sl) * HD + d];
  }
  __syncthreads();
  for (int it = 0; it < 32; ++it) {
    int idx = tid + it * 256;  // 128 d x 64 s
    int d = idx >> 6, sl = idx & 63;
    Vt[((size_t)kvh * HD + d) * S + s0 + sl] = Lt[d][sl];
  }
}

// ---------------------------------------------------------------------------
// MFMA flash attention with register prefetch of next K/V tile.
// Block = (64 q-rows, head); 4 waves x 16 q-rows. AO written as bf16.
// ---------------------------------------------------------------------------
__global__ __launch_bounds__(256) void attn_mfma(
    const unsigned short* __restrict__ Qh, const unsigned short* __restrict__ Ql,
    const unsigned short* __restrict__ Kh, const unsigned short* __restrict__ Kl,
    const unsigned short* __restrict__ Vt, unsigned short* __restrict__ AOh,
    float* __restrict__ mbuf, float* __restrict__ lbuf) {
  const int qt = blockIdx.x, h = blockIdx.y;
  const int kvh = h / GROUPS;
  const int tid = threadIdx.x;
  const int lane = tid & 63, w = tid >> 6;
  const int quad = lane >> 4, l16 = lane & 15;
  const int q0 = qt * 64;

  __shared__ __align__(16) unsigned short smem[31232];  // 62464 B
  unsigned short* sQh = smem;
  unsigned short* sQl = smem + 8704;
  unsigned short* sKh = smem;             // reuse after Q frags read
  unsigned short* sKl = smem + 8704;
  unsigned short* sVt = smem + 17408;     // 128 x 72
  unsigned short* sP  = smem + 26624;     // 4 waves x 16 x 72

  // prefetch K/V tile 0 into registers (overlaps with Q staging)
  ushort8 pKh[4], pKl[4], pV[4];
#pragma unroll
  for (int it = 0; it < 4; ++it) {
    int idx = tid + it * 256;
    int r = idx >> 4, c8 = idx & 15;
    size_t g = ((size_t)kvh * S + r) * HD + c8 * 8;
    pKh[it] = *(const ushort8*)&Kh[g];
    pKl[it] = *(const ushort8*)&Kl[g];
  }
#pragma unroll
  for (int it = 0; it < 4; ++it) {
    int idx = tid + it * 256;
    int d = idx >> 3, c8 = idx & 7;
    size_t g = ((size_t)kvh * HD + d) * S + c8 * 8;
    pV[it] = *(const ushort8*)&Vt[g];
  }

  // stage Q tile, read A-frags
#pragma unroll
  for (int it = 0; it < 4; ++it) {
    int idx = tid + it * 256;
    int r = idx >> 4, c8 = idx & 15;
    size_t g = (size_t)(q0 + r) * NQ + h * HD + c8 * 8;
    int li = r * 136 + c8 * 8;
    *(ushort8*)&sQh[li] = *(const ushort8*)&Qh[g];
    *(ushort8*)&sQl[li] = *(const ushort8*)&Ql[g];
  }
  __syncthreads();
  bf16x8 fqh[4], fql[4];
#pragma unroll
  for (int d4 = 0; d4 < 4; ++d4) {
    int a = (w * 16 + l16) * 136 + d4 * 32 + quad * 8;
    fqh[d4] = *(bf16x8*)&sQh[a];
    fql[d4] = *(bf16x8*)&sQl[a];
  }

  f32x4 O[8];
#pragma unroll
  for (int jn = 0; jn < 8; ++jn) O[jn] = (f32x4){0.f, 0.f, 0.f, 0.f};
  float m_[4], l_[4];
#pragma unroll
  for (int r = 0; r < 4; ++r) { m_[r] = -INFINITY; l_[r] = 0.f; }

  const int row_l = w * 16 + quad * 4;
  const int wbase = w * 1152;

  for (int kt = 0; kt <= qt; ++kt) {
    __syncthreads();  // previous tile's LDS consumers done (or Q-frag reads)
    // commit prefetched tile to LDS
#pragma unroll
    for (int it = 0; it < 4; ++it) {
      int idx = tid + it * 256;
      int r = idx >> 4, c8 = idx & 15;
      *(ushort8*)&sKh[r * 136 + c8 * 8] = pKh[it];
      *(ushort8*)&sKl[r * 136 + c8 * 8] = pKl[it];
    }
#pragma unroll
    for (int it = 0; it < 4; ++it) {
      int idx = tid + it * 256;
      int d = idx >> 3, c8 = idx & 7;
      *(ushort8*)&sVt[d * 72 + c8 * 8] = pV[it];
    }
    __syncthreads();
    // issue next tile's global loads (hidden under compute below)
    if (kt < qt) {
#pragma unroll
      for (int it = 0; it < 4; ++it) {
        int idx = tid + it * 256;
        int r = idx >> 4, c8 = idx & 15;
        size_t g = ((size_t)kvh * S + (kt + 1) * 64 + r) * HD + c8 * 8;
        pKh[it] = *(const ushort8*)&Kh[g];
        pKl[it] = *(const ushort8*)&Kl[g];
      }
#pragma unroll
      for (int it = 0; it < 4; ++it) {
        int idx = tid + it * 256;
        int d = idx >> 3, c8 = idx & 7;
        size_t g = ((size_t)kvh * HD + d) * S + (kt + 1) * 64 + c8 * 8;
        pV[it] = *(const ushort8*)&Vt[g];
      }
    }

    // S = Q K^T (split 3-term)
    f32x4 sc[4];
#pragma unroll
    for (int j = 0; j < 4; ++j) sc[j] = (f32x4){0.f, 0.f, 0.f, 0.f};
#pragma unroll
    for (int d4 = 0; d4 < 4; ++d4) {
#pragma unroll
      for (int j = 0; j < 4; ++j) {
        int b = (j * 16 + l16) * 136 + d4 * 32 + quad * 8;
        bf16x8 bh = *(bf16x8*)&sKh[b];
        bf16x8 bl = *(bf16x8*)&sKl[b];
        sc[j] = __builtin_amdgcn_mfma_f32_16x16x32_bf16(fqh[d4], bh, sc[j], 0, 0, 0);
        sc[j] = __builtin_amdgcn_mfma_f32_16x16x32_bf16(fqh[d4], bl, sc[j], 0, 0, 0);
        sc[j] = __builtin_amdgcn_mfma_f32_16x16x32_bf16(fql[d4], bh, sc[j], 0, 0, 0);
      }
    }
    const bool diag = (kt == qt);
#pragma unroll
    for (int j = 0; j < 4; ++j) {
      int col_l = j * 16 + l16;
#pragma unroll
      for (int r = 0; r < 4; ++r) {
        float v = sc[j][r] * SCALE;
        if (diag && col_l > row_l + r) v = -INFINITY;
        sc[j][r] = v;
      }
    }
    float tm[4];
#pragma unroll
    for (int r = 0; r < 4; ++r) {
      float t = sc[0][r];
#pragma unroll
      for (int j = 1; j < 4; ++j) t = fmaxf(t, sc[j][r]);
      tm[r] = t;
    }
#pragma unroll
    for (int off = 1; off < 16; off <<= 1)
#pragma unroll
      for (int r = 0; r < 4; ++r) tm[r] = fmaxf(tm[r], __shfl_xor(tm[r], off));
    float alpha[4];
#pragma unroll
    for (int r = 0; r < 4; ++r) {
      float mn = fmaxf(m_[r], tm[r]);
      alpha[r] = __expf(m_[r] - mn);
      m_[r] = mn;
    }
    float psum[4] = {0.f, 0.f, 0.f, 0.f};
#pragma unroll
    for (int j = 0; j < 4; ++j)
#pragma unroll
      for (int r = 0; r < 4; ++r) {
        float p = __expf(sc[j][r] - m_[r]);
        sc[j][r] = p;
        psum[r] += p;
      }
#pragma unroll
    for (int off = 1; off < 16; off <<= 1)
#pragma unroll
      for (int r = 0; r < 4; ++r) psum[r] += __shfl_xor(psum[r], off);
#pragma unroll
    for (int r = 0; r < 4; ++r) l_[r] = l_[r] * alpha[r] + psum[r];
#pragma unroll
    for (int jn = 0; jn < 8; ++jn)
#pragma unroll
      for (int r = 0; r < 4; ++r) O[jn][r] *= alpha[r];
#pragma unroll
    for (int j = 0; j < 4; ++j)
#pragma unroll
      for (int r = 0; r < 4; ++r)
        sP[wbase + (quad * 4 + r) * 72 + j * 16 + l16] = f2b(sc[j][r]);
    bf16x8 ap0 = *(bf16x8*)&sP[wbase + l16 * 72 + quad * 8];
    bf16x8 ap1 = *(bf16x8*)&sP[wbase + l16 * 72 + 32 + quad * 8];
#pragma unroll
    for (int jn = 0; jn < 8; ++jn) {
      bf16x8 bv0 = *(bf16x8*)&sVt[(jn * 16 + l16) * 72 + quad * 8];
      bf16x8 bv1 = *(bf16x8*)&sVt[(jn * 16 + l16) * 72 + 32 + quad * 8];
      O[jn] = __builtin_amdgcn_mfma_f32_16x16x32_bf16(ap0, bv0, O[jn], 0, 0, 0);
      O[jn] = __builtin_amdgcn_mfma_f32_16x16x32_bf16(ap1, bv1, O[jn], 0, 0, 0);
    }
  }
  float linv[4];
#pragma unroll
  for (int r = 0; r < 4; ++r) linv[r] = 1.0f / l_[r];
#pragma unroll
  for (int jn = 0; jn < 8; ++jn)
#pragma unroll
    for (int r = 0; r < 4; ++r)
      AOh[(size_t)(q0 + row_l + r) * NQ + h * HD + jn * 16 + l16] =
          f2b(O[jn][r] * linv[r]);
  if (l16 == 0) {
#pragma unroll
    for (int r = 0; r < 4; ++r) {
      mbuf[h * S + q0 + row_l + r] = m_[r];
      lbuf[h * S + q0 + row_l + r] = l_[r];
    }
  }
}

// ---------------------------------------------------------------------------
// MFMA cur pass with register prefetch of next Q tile.
// ---------------------------------------------------------------------------
__global__ __launch_bounds__(256) void cur_mfma(
    const unsigned short* __restrict__ Qh, const unsigned short* __restrict__ Ql,
    const unsigned short* __restrict__ Kh, const unsigned short* __restrict__ Kl,
    const float* __restrict__ mbuf, const float* __restrict__ lbuf,
    float* __restrict__ cur) {
  const int kt = blockIdx.x, h = blockIdx.y;
  const int kvh = h / GROUPS;
  const int tid = threadIdx.x;
  const int lane = tid & 63, w = tid >> 6;
  const int quad = lane >> 4, l16 = lane & 15;

  __shared__ __align__(16) unsigned short sKh[8704];
  __shared__ __align__(16) unsigned short sKl[8704];
  __shared__ __align__(16) unsigned short sQh[8704];
  __shared__ __align__(16) unsigned short sQl[8704];
  __shared__ float smq[64], slinv[64];

#pragma unroll
  for (int it = 0; it < 4; ++it) {
    int idx = tid + it * 256;
    int r = idx >> 4, c8 = idx & 15;
    size_t g = ((size_t)kvh * S + kt * 64 + r) * HD + c8 * 8;
    int li = r * 136 + c8 * 8;
    *(ushort8*)&sKh[li] = *(const ushort8*)&Kh[g];
    *(ushort8*)&sKl[li] = *(const ushort8*)&Kl[g];
  }
  __syncthreads();
  bf16x8 fkh[4], fkl[4];
#pragma unroll
  for (int d4 = 0; d4 < 4; ++d4) {
    int a = (w * 16 + l16) * 136 + d4 * 32 + quad * 8;
    fkh[d4] = *(bf16x8*)&sKh[a];
    fkl[d4] = *(bf16x8*)&sKl[a];
  }

  const int krow_l = w * 16 + quad * 4;
  float csum[4] = {0.f, 0.f, 0.f, 0.f};

  // prefetch first q-tile
  ushort8 pQh[4], pQl[4];
  float pm = 0.f, pli = 0.f;
#pragma unroll
  for (int it = 0; it < 4; ++it) {
    int idx = tid + it * 256;
    int r = idx >> 4, c8 = idx & 15;
    size_t g = (size_t)(kt * 64 + r) * NQ + h * HD + c8 * 8;
    pQh[it] = *(const ushort8*)&Qh[g];
    pQl[it] = *(const ushort8*)&Ql[g];
  }
  if (tid < 64) {
    pm = mbuf[h * S + kt * 64 + tid];
    pli = 1.0f / lbuf[h * S + kt * 64 + tid];
  }

  for (int qt = kt; qt < S / 64; ++qt) {
    __syncthreads();
#pragma unroll
    for (int it = 0; it < 4; ++it) {
      int idx = tid + it * 256;
      int r = idx >> 4, c8 = idx & 15;
      int li = r * 136 + c8 * 8;
      *(ushort8*)&sQh[li] = pQh[it];
      *(ushort8*)&sQl[li] = pQl[it];
    }
    if (tid < 64) { smq[tid] = pm; slinv[tid] = pli; }
    __syncthreads();
    if (qt + 1 < S / 64) {
#pragma unroll
      for (int it = 0; it < 4; ++it) {
        int idx = tid + it * 256;
        int r = idx >> 4, c8 = idx & 15;
        size_t g = (size_t)((qt + 1) * 64 + r) * NQ + h * HD + c8 * 8;
        pQh[it] = *(const ushort8*)&Qh[g];
        pQl[it] = *(const ushort8*)&Ql[g];
      }
      if (tid < 64) {
        pm = mbuf[h * S + (qt + 1) * 64 + tid];
        pli = 1.0f / lbuf[h * S + (qt + 1) * 64 + tid];
      }
    }
    f32x4 sc[4];
#pragma unroll
    for (int j = 0; j < 4; ++j) sc[j] = (f32x4){0.f, 0.f, 0.f, 0.f};
#pragma unroll
    for (int d4 = 0; d4 < 4; ++d4) {
#pragma unroll
      for (int j = 0; j < 4; ++j) {
        int b = (j * 16 + l16) * 136 + d4 * 32 + quad * 8;
        bf16x8 bh = *(bf16x8*)&sQh[b];
        bf16x8 bl = *(bf16x8*)&sQl[b];
        sc[j] = __builtin_amdgcn_mfma_f32_16x16x32_bf16(fkh[d4], bh, sc[j], 0, 0, 0);
        sc[j] = __builtin_amdgcn_mfma_f32_16x16x32_bf16(fkh[d4], bl, sc[j], 0, 0, 0);
        sc[j] = __builtin_amdgcn_mfma_f32_16x16x32_bf16(fkl[d4], bh, sc[j], 0, 0, 0);
      }
    }
    const bool diag = (qt == kt);
#pragma unroll
    for (int j = 0; j < 4; ++j) {
      int qcol_l = j * 16 + l16;
      float mqv = smq[qcol_l];
      float lv = slinv[qcol_l];
#pragma unroll
      for (int r = 0; r < 4; ++r) {
        float p = __expf(sc[j][r] * SCALE - mqv) * lv;
        if (diag && (krow_l + r) > qcol_l) p = 0.f;
        csum[r] += p;
      }
    }
  }
#pragma unroll
  for (int off = 1; off < 16; off <<= 1)
#pragma unroll
    for (int r = 0; r < 4; ++r) csum[r] += __shfl_xor(csum[r], off);
  if (l16 == 0) {
#pragma unroll
    for (int r = 0; r < 4; ++r)
      cur[h * S + kt * 64 + krow_l + r] = csum[r];
  }
}

// ---------------------------------------------------------------------------
// top-k + mask (unchanged, verified)
// ---------------------------------------------------------------------------
__global__ __launch_bounds__(256) void topk_kernel(
    const float* __restrict__ cur, float* __restrict__ mask) {
  const int h = blockIdx.x;
  const int tid = threadIdx.x;
  __shared__ unsigned uv[SKEEP];
  __shared__ int red[256];

  for (int i = tid; i < SKEEP; i += 256) uv[i] = __float_as_uint(cur[h * S + i]);
  __syncthreads();

  unsigned lo = 0u, hi = 0xffffffffu;
  while (lo < hi) {
    unsigned mid = (unsigned)((((unsigned long long)lo + hi) + 1ull) >> 1);
    int c = 0;
    for (int i = tid; i < SKEEP; i += 256) c += (uv[i] >= mid) ? 1 : 0;
    red[tid] = c;
    __syncthreads();
    for (int s = 128; s > 0; s >>= 1) {
      if (tid < s) red[tid] += red[tid + s];
      __syncthreads();
    }
    int cnt = red[0];
    __syncthreads();
    if (cnt >= HEAVY) lo = mid; else hi = mid - 1;
  }
  const unsigned vk = lo;
  int c = 0;
  for (int i = tid; i < SKEEP; i += 256) c += (uv[i] > vk) ? 1 : 0;
  red[tid] = c;
  __syncthreads();
  for (int s = 128; s > 0; s >>= 1) {
    if (tid < s) red[tid] += red[tid + s];
    __syncthreads();
  }
  const int cgt = red[0];
  __syncthreads();
  const int r = HEAVY - cgt;

  for (int j = tid; j < MASKC; j += 256)
    mask[(size_t)h * MASKC + j] = (j >= MASKC - RECENT) ? 1.0f : 0.0f;
  __syncthreads();
  for (int i = tid; i < SKEEP; i += 256)
    if (uv[i] > vk) mask[(size_t)h * MASKC + i] = 1.0f;
  if (tid == 0) {
    int rem = r;
    for (int i = 0; i < SKEEP && rem > 0; ++i) {
      if (uv[i] == vk) { mask[(size_t)h * MASKC + i] = 1.0f; --rem; }
    }
  }
}

// ---------------------------------------------------------------------------
extern "C" void kernel_launch(void* const* d_in, const int* in_sizes, int n_in,
                              void* d_out, int out_size, void* d_ws,
                              size_t ws_size, hipStream_t stream) {
  const float* hs  = (const float*)d_in[0];
  const float* q_w = (const float*)d_in[1];
  const float* q_b = (const float*)d_in[2];
  const float* k_w = (const float*)d_in[3];
  const float* k_b = (const float*)d_in[4];
  const float* v_w = (const float*)d_in[5];
  const float* v_b = (const float*)d_in[6];
  const float* o_w = (const float*)d_in[7];

  char* ws = (char*)d_ws;
  unsigned short* Qh   = (unsigned short*)(ws + 0);           //  8,388,608
  unsigned short* Ql   = (unsigned short*)(ws + 8388608);     //  8,388,608
  unsigned short* Kh   = (unsigned short*)(ws + 16777216);    //  2,097,152
  unsigned short* Kl   = (unsigned short*)(ws + 18874368);    //  2,097,152
  unsigned short* Vrow = (unsigned short*)(ws + 20971520);    //  2,097,152
  unsigned short* Vt   = (unsigned short*)(ws + 23068672);    //  2,097,152
  unsigned short* AOh  = (unsigned short*)(ws + 25165824);    //  8,388,608
  float* mb   = (float*)(ws + 33554432);                      //    131,072
  float* lb   = (float*)(ws + 33685504);                      //    131,072
  float* cur  = (float*)(ws + 33816576);                      //    131,072
  float* bcat = (float*)(ws + 33947648);                      //     12,288
  char* pool = ws + 33959936;
  unsigned short* hsh = (unsigned short*)pool;                //  8,388,608
  unsigned short* hsl = (unsigned short*)(pool + 8388608);    //  8,388,608
  unsigned short* WTh = (unsigned short*)(pool + 16777216);   // 12,582,912
  unsigned short* WTl = (unsigned short*)(pool + 29360128);   // 12,582,912
  unsigned short* OTh = (unsigned short*)pool;  // alias hsh (dead after gemm_qkv)

  float* outp  = (float*)d_out;
  float* maskp = outp + (size_t)S * D;

  dim3 blk(256);
  // 1. split inputs
  split_act<<<dim3(2048), blk, 0, stream>>>(hs, hsh, hsl, S * D);
  split_wT<<<dim3(NQ / 64, D / 64), blk, 0, stream>>>(q_w, WTh, WTl, D, NQ, 0, D);
  split_wT<<<dim3(NKV / 64, D / 64), blk, 0, stream>>>(k_w, WTh, WTl, D, NKV, NQ, D);
  split_wT<<<dim3(NKV / 64, D / 64), blk, 0, stream>>>(v_w, WTh, WTl, D, NKV, NQ + NKV, D);
  concat_bias<<<dim3((N3 + 255) / 256), blk, 0, stream>>>(q_b, k_b, v_b, bcat);
  // 2. fused QKV projection writing split-bf16 attention operands directly
  gemm_qkv<<<dim3(N3 / 128, S / 128), blk, 0, stream>>>(
      hsh, hsl, WTh, WTl, bcat, Qh, Ql, Kh, Kl, Vrow, S, N3, D);
  prep_vt<<<dim3(S / 64, KVH), blk, 0, stream>>>(Vrow, Vt);
  // o_w transpose can overlap; OTh aliases hsh which is dead after gemm_qkv
  wT_bf16<<<dim3(D / 64, NQ / 64), blk, 0, stream>>>(o_w, OTh, NQ, D);
  // 3. attention (writes bf16 AO)
  attn_mfma<<<dim3(S / 64, H), blk, 0, stream>>>(Qh, Ql, Kh, Kl, Vt, AOh, mb, lb);
  // 4. cur scores + topk mask
  cur_mfma<<<dim3((SKEEP + 63) / 64, H), blk, 0, stream>>>(Qh, Ql, Kh, Kl, mb, lb, cur);
  topk_kernel<<<dim3(H), blk, 0, stream>>>(cur, maskp);
  // 5. output projection (plain bf16)
  gemm_bf16<<<dim3(D / 128, S / 128), blk, 0, stream>>>(AOh, OTh, outp, S, D, NQ);
}

// Round 6
// 460.182 us; speedup vs baseline: 11.7068x; 1.1050x over previous
//
#include <hip/hip_runtime.h>
#include <hip/hip_bf16.h>
#include <math.h>

// Problem constants
constexpr int S   = 2048;
constexpr int D   = 2048;
constexpr int H   = 16;
constexpr int KVH = 4;
constexpr int HD  = 128;
constexpr int NQ  = H * HD;      // 2048
constexpr int NKV = KVH * HD;    // 512
constexpr int N3  = NQ + 2 * NKV; // 3072
constexpr int GROUPS = H / KVH;   // 4
constexpr float SCALE = 0.088388347648318447f; // 128^-0.5
constexpr int HEAVY  = 204;
constexpr int RECENT = 204;
constexpr int SKEEP  = S - RECENT;  // 1844
constexpr int MASKC  = S + 1;       // 2049

typedef short bf16x8 __attribute__((ext_vector_type(8)));
typedef unsigned short ushort8 __attribute__((ext_vector_type(8)));
typedef float f32x4 __attribute__((ext_vector_type(4)));

__device__ __forceinline__ unsigned short f2b(float x) {
  __hip_bfloat16 h = __float2bfloat16(x);
  return *(unsigned short*)&h;
}
__device__ __forceinline__ float b2f(unsigned short u) {
  __hip_bfloat16 h = *(__hip_bfloat16*)&u;
  return __bfloat162float(h);
}

// ---------------------------------------------------------------------------
// split_act: fp32 [n] -> bf16 hi/lo pair (hidden states)
// ---------------------------------------------------------------------------
__global__ __launch_bounds__(256) void split_act(
    const float* __restrict__ in, unsigned short* __restrict__ oh,
    unsigned short* __restrict__ ol, int n) {
  for (int i = blockIdx.x * 256 + threadIdx.x; i < n; i += gridDim.x * 256) {
    float x = in[i];
    unsigned short h = f2b(x);
    oh[i] = h;
    ol[i] = f2b(x - b2f(h));
  }
}

// ---------------------------------------------------------------------------
// split_wT: in[K][N] fp32 -> out[rowOff + n][k] bf16 hi/lo (transposed split)
// ---------------------------------------------------------------------------
__global__ __launch_bounds__(256) void split_wT(
    const float* __restrict__ in, unsigned short* __restrict__ oh,
    unsigned short* __restrict__ ol, int K, int N, int rowOff, int ldOut) {
  __shared__ float Lt[64][65];
  const int n0 = blockIdx.x * 64, k0 = blockIdx.y * 64;
  const int t = threadIdx.x;
  const int cq = t & 15, r4 = t >> 4;
#pragma unroll
  for (int i = 0; i < 4; ++i) {
    int r = r4 + i * 16;
    float4 v = *(const float4*)&in[(size_t)(k0 + r) * N + n0 + cq * 4];
    Lt[cq * 4 + 0][r] = v.x;
    Lt[cq * 4 + 1][r] = v.y;
    Lt[cq * 4 + 2][r] = v.z;
    Lt[cq * 4 + 3][r] = v.w;
  }
  __syncthreads();
#pragma unroll
  for (int i = 0; i < 4; ++i) {
    int rr = r4 + i * 16;
    size_t base = (size_t)(rowOff + n0 + rr) * ldOut + k0 + cq * 4;
#pragma unroll
    for (int j = 0; j < 4; ++j) {
      float x = Lt[rr][cq * 4 + j];
      unsigned short h = f2b(x);
      oh[base + j] = h;
      ol[base + j] = f2b(x - b2f(h));
    }
  }
}

// ---------------------------------------------------------------------------
// wT_bf16: in[K][N] fp32 -> out[n][k] bf16 (hi only) — for o_w
// ---------------------------------------------------------------------------
__global__ __launch_bounds__(256) void wT_bf16(
    const float* __restrict__ in, unsigned short* __restrict__ oh,
    int K, int N) {
  __shared__ float Lt[64][65];
  const int n0 = blockIdx.x * 64, k0 = blockIdx.y * 64;
  const int t = threadIdx.x;
  const int cq = t & 15, r4 = t >> 4;
#pragma unroll
  for (int i = 0; i < 4; ++i) {
    int r = r4 + i * 16;
    float4 v = *(const float4*)&in[(size_t)(k0 + r) * N + n0 + cq * 4];
    Lt[cq * 4 + 0][r] = v.x;
    Lt[cq * 4 + 1][r] = v.y;
    Lt[cq * 4 + 2][r] = v.z;
    Lt[cq * 4 + 3][r] = v.w;
  }
  __syncthreads();
#pragma unroll
  for (int i = 0; i < 4; ++i) {
    int rr = r4 + i * 16;
    size_t base = (size_t)(n0 + rr) * K + k0 + cq * 4;
#pragma unroll
    for (int j = 0; j < 4; ++j) oh[base + j] = f2b(Lt[rr][cq * 4 + j]);
  }
}

// ---------------------------------------------------------------------------
// concat_bias
// ---------------------------------------------------------------------------
__global__ void concat_bias(const float* qb, const float* kb, const float* vb,
                            float* out) {
  int i = blockIdx.x * 256 + threadIdx.x;
  if (i < NQ) out[i] = qb[i];
  else if (i < NQ + NKV) out[i] = kb[i - NQ];
  else if (i < N3) out[i] = vb[i - NQ - NKV];
}

// ---------------------------------------------------------------------------
// QKV GEMM (split-bf16, 3 MFMA) with fused epilogue (unchanged from R5)
// ---------------------------------------------------------------------------
__global__ __launch_bounds__(256) void gemm_qkv(
    const unsigned short* __restrict__ Ah, const unsigned short* __restrict__ Al,
    const unsigned short* __restrict__ Bh, const unsigned short* __restrict__ Bl,
    const float* __restrict__ bias,
    unsigned short* __restrict__ Qh, unsigned short* __restrict__ Ql,
    unsigned short* __restrict__ Kh, unsigned short* __restrict__ Kl,
    unsigned short* __restrict__ Vrow, int M, int N, int K) {
  __shared__ __align__(16) unsigned short sAh[128 * 40];
  __shared__ __align__(16) unsigned short sAl[128 * 40];
  __shared__ __align__(16) unsigned short sBh[128 * 40];
  __shared__ __align__(16) unsigned short sBl[128 * 40];
  const int tid = threadIdx.x;
  const int lane = tid & 63, wave = tid >> 6;
  const int wm = wave >> 1, wn = wave & 1;
  const int quad = lane >> 4, l16 = lane & 15;
  const int m0 = blockIdx.y * 128, n0 = blockIdx.x * 128;

  f32x4 acc[4][4];
#pragma unroll
  for (int i = 0; i < 4; ++i)
#pragma unroll
    for (int j = 0; j < 4; ++j) acc[i][j] = (f32x4){0.f, 0.f, 0.f, 0.f};

  for (int k0 = 0; k0 < K; k0 += 32) {
#pragma unroll
    for (int it = 0; it < 2; ++it) {
      int c = tid + it * 256;
      int r = c >> 2, sub = c & 3;
      size_t ga = (size_t)(m0 + r) * K + k0 + sub * 8;
      size_t gb = (size_t)(n0 + r) * K + k0 + sub * 8;
      int li = r * 40 + sub * 8;
      *(ushort8*)&sAh[li] = *(const ushort8*)&Ah[ga];
      *(ushort8*)&sAl[li] = *(const ushort8*)&Al[ga];
      *(ushort8*)&sBh[li] = *(const ushort8*)&Bh[gb];
      *(ushort8*)&sBl[li] = *(const ushort8*)&Bl[gb];
    }
    __syncthreads();
    bf16x8 fah[4], fal[4], fbh[4], fbl[4];
#pragma unroll
    for (int i = 0; i < 4; ++i) {
      int ra = (wm * 64 + i * 16 + l16) * 40 + quad * 8;
      fah[i] = *(bf16x8*)&sAh[ra];
      fal[i] = *(bf16x8*)&sAl[ra];
      int rb = (wn * 64 + i * 16 + l16) * 40 + quad * 8;
      fbh[i] = *(bf16x8*)&sBh[rb];
      fbl[i] = *(bf16x8*)&sBl[rb];
    }
#pragma unroll
    for (int i = 0; i < 4; ++i)
#pragma unroll
      for (int j = 0; j < 4; ++j) {
        acc[i][j] = __builtin_amdgcn_mfma_f32_16x16x32_bf16(fah[i], fbh[j], acc[i][j], 0, 0, 0);
        acc[i][j] = __builtin_amdgcn_mfma_f32_16x16x32_bf16(fah[i], fbl[j], acc[i][j], 0, 0, 0);
        acc[i][j] = __builtin_amdgcn_mfma_f32_16x16x32_bf16(fal[i], fbh[j], acc[i][j], 0, 0, 0);
      }
    __syncthreads();
  }
#pragma unroll
  for (int i = 0; i < 4; ++i) {
#pragma unroll
    for (int j = 0; j < 4; ++j) {
      int row = m0 + wm * 64 + i * 16 + quad * 4;
      int col = n0 + wn * 64 + j * 16 + l16;
      float bv = bias[col];
#pragma unroll
      for (int r = 0; r < 4; ++r) {
        float x = acc[i][j][r] + bv;
        unsigned short hb = f2b(x);
        unsigned short lb2 = f2b(x - b2f(hb));
        if (n0 < NQ) {
          size_t o = (size_t)(row + r) * NQ + col;
          Qh[o] = hb; Ql[o] = lb2;
        } else if (n0 < NQ + NKV) {
          int c = col - NQ;
          size_t o = ((size_t)(c >> 7) * S + row + r) * HD + (c & 127);
          Kh[o] = hb; Kl[o] = lb2;
        } else {
          int c = col - NQ - NKV;
          size_t o = ((size_t)(c >> 7) * S + row + r) * HD + (c & 127);
          Vrow[o] = hb;
        }
      }
    }
  }
}

// ---------------------------------------------------------------------------
// Plain bf16 GEMM for output projection (unchanged from R5)
// ---------------------------------------------------------------------------
__global__ __launch_bounds__(256) void gemm_bf16(
    const unsigned short* __restrict__ Ah, const unsigned short* __restrict__ Bh,
    float* __restrict__ C, int M, int N, int K) {
  __shared__ __align__(16) unsigned short sA[128 * 40];
  __shared__ __align__(16) unsigned short sB[128 * 40];
  const int tid = threadIdx.x;
  const int lane = tid & 63, wave = tid >> 6;
  const int wm = wave >> 1, wn = wave & 1;
  const int quad = lane >> 4, l16 = lane & 15;
  const int m0 = blockIdx.y * 128, n0 = blockIdx.x * 128;

  f32x4 acc[4][4];
#pragma unroll
  for (int i = 0; i < 4; ++i)
#pragma unroll
    for (int j = 0; j < 4; ++j) acc[i][j] = (f32x4){0.f, 0.f, 0.f, 0.f};

  for (int k0 = 0; k0 < K; k0 += 32) {
#pragma unroll
    for (int it = 0; it < 2; ++it) {
      int c = tid + it * 256;
      int r = c >> 2, sub = c & 3;
      size_t ga = (size_t)(m0 + r) * K + k0 + sub * 8;
      size_t gb = (size_t)(n0 + r) * K + k0 + sub * 8;
      int li = r * 40 + sub * 8;
      *(ushort8*)&sA[li] = *(const ushort8*)&Ah[ga];
      *(ushort8*)&sB[li] = *(const ushort8*)&Bh[gb];
    }
    __syncthreads();
    bf16x8 fa[4], fb[4];
#pragma unroll
    for (int i = 0; i < 4; ++i) {
      fa[i] = *(bf16x8*)&sA[(wm * 64 + i * 16 + l16) * 40 + quad * 8];
      fb[i] = *(bf16x8*)&sB[(wn * 64 + i * 16 + l16) * 40 + quad * 8];
    }
#pragma unroll
    for (int i = 0; i < 4; ++i)
#pragma unroll
      for (int j = 0; j < 4; ++j)
        acc[i][j] = __builtin_amdgcn_mfma_f32_16x16x32_bf16(fa[i], fb[j], acc[i][j], 0, 0, 0);
    __syncthreads();
  }
#pragma unroll
  for (int i = 0; i < 4; ++i)
#pragma unroll
    for (int j = 0; j < 4; ++j) {
      int row = m0 + wm * 64 + i * 16 + quad * 4;
      int col = n0 + wn * 64 + j * 16 + l16;
#pragma unroll
      for (int r = 0; r < 4; ++r)
        C[(size_t)(row + r) * N + col] = acc[i][j][r];
    }
}

// ---------------------------------------------------------------------------
// prep_vt: Vrow bf16 [kvh][s][d] -> Vt bf16 [kvh][d][S]
// ---------------------------------------------------------------------------
__global__ __launch_bounds__(256) void prep_vt(
    const unsigned short* __restrict__ Vrow, unsigned short* __restrict__ Vt) {
  __shared__ unsigned short Lt[128][66];
  const int s0 = blockIdx.x * 64, kvh = blockIdx.y;
  const int tid = threadIdx.x;
  for (int it = 0; it < 32; ++it) {
    int idx = tid + it * 256;
    int sl = idx >> 7, d = idx & 127;
    Lt[d][sl] = Vrow[((size_t)kvh * S + s0 + sl) * HD + d];
  }
  __syncthreads();
  for (int it = 0; it < 32; ++it) {
    int idx = tid + it * 256;
    int d = idx >> 6, sl = idx & 63;
    Vt[((size_t)kvh * HD + d) * S + s0 + sl] = Lt[d][sl];
  }
}

// ---------------------------------------------------------------------------
// MFMA flash attention. Flat 512-block grid with anti-diagonal (qt,h) remap:
// co-resident blocks (x, x+256) get qt and 31-qt -> uniform 33 k-tiles/CU.
// ---------------------------------------------------------------------------
__global__ __launch_bounds__(256) void attn_mfma(
    const unsigned short* __restrict__ Qh, const unsigned short* __restrict__ Ql,
    const unsigned short* __restrict__ Kh, const unsigned short* __restrict__ Kl,
    const unsigned short* __restrict__ Vt, unsigned short* __restrict__ AOh,
    float* __restrict__ mbuf, float* __restrict__ lbuf) {
  const int x = blockIdx.x;
  const int base = x & 255;
  const int qt0 = base & 31, h0 = base >> 5;
  const int qt = (x < 256) ? qt0 : 31 - qt0;
  const int h  = (x < 256) ? h0 : h0 + 8;
  const int kvh = h / GROUPS;
  const int tid = threadIdx.x;
  const int lane = tid & 63, w = tid >> 6;
  const int quad = lane >> 4, l16 = lane & 15;
  const int q0 = qt * 64;

  __shared__ __align__(16) unsigned short smem[31232];  // 62464 B
  unsigned short* sQh = smem;
  unsigned short* sQl = smem + 8704;
  unsigned short* sKh = smem;             // reuse after Q frags read
  unsigned short* sKl = smem + 8704;
  unsigned short* sVt = smem + 17408;     // 128 x 72
  unsigned short* sP  = smem + 26624;     // 4 waves x 16 x 72

  // prefetch K/V tile 0 into registers (overlaps with Q staging)
  ushort8 pKh[4], pKl[4], pV[4];
#pragma unroll
  for (int it = 0; it < 4; ++it) {
    int idx = tid + it * 256;
    int r = idx >> 4, c8 = idx & 15;
    size_t g = ((size_t)kvh * S + r) * HD + c8 * 8;
    pKh[it] = *(const ushort8*)&Kh[g];
    pKl[it] = *(const ushort8*)&Kl[g];
  }
#pragma unroll
  for (int it = 0; it < 4; ++it) {
    int idx = tid + it * 256;
    int d = idx >> 3, c8 = idx & 7;
    size_t g = ((size_t)kvh * HD + d) * S + c8 * 8;
    pV[it] = *(const ushort8*)&Vt[g];
  }

  // stage Q tile, read A-frags
#pragma unroll
  for (int it = 0; it < 4; ++it) {
    int idx = tid + it * 256;
    int r = idx >> 4, c8 = idx & 15;
    size_t g = (size_t)(q0 + r) * NQ + h * HD + c8 * 8;
    int li = r * 136 + c8 * 8;
    *(ushort8*)&sQh[li] = *(const ushort8*)&Qh[g];
    *(ushort8*)&sQl[li] = *(const ushort8*)&Ql[g];
  }
  __syncthreads();
  bf16x8 fqh[4], fql[4];
#pragma unroll
  for (int d4 = 0; d4 < 4; ++d4) {
    int a = (w * 16 + l16) * 136 + d4 * 32 + quad * 8;
    fqh[d4] = *(bf16x8*)&sQh[a];
    fql[d4] = *(bf16x8*)&sQl[a];
  }

  f32x4 O[8];
#pragma unroll
  for (int jn = 0; jn < 8; ++jn) O[jn] = (f32x4){0.f, 0.f, 0.f, 0.f};
  float m_[4], l_[4];
#pragma unroll
  for (int r = 0; r < 4; ++r) { m_[r] = -INFINITY; l_[r] = 0.f; }

  const int row_l = w * 16 + quad * 4;
  const int wbase = w * 1152;

  for (int kt = 0; kt <= qt; ++kt) {
    __syncthreads();
#pragma unroll
    for (int it = 0; it < 4; ++it) {
      int idx = tid + it * 256;
      int r = idx >> 4, c8 = idx & 15;
      *(ushort8*)&sKh[r * 136 + c8 * 8] = pKh[it];
      *(ushort8*)&sKl[r * 136 + c8 * 8] = pKl[it];
    }
#pragma unroll
    for (int it = 0; it < 4; ++it) {
      int idx = tid + it * 256;
      int d = idx >> 3, c8 = idx & 7;
      *(ushort8*)&sVt[d * 72 + c8 * 8] = pV[it];
    }
    __syncthreads();
    if (kt < qt) {
#pragma unroll
      for (int it = 0; it < 4; ++it) {
        int idx = tid + it * 256;
        int r = idx >> 4, c8 = idx & 15;
        size_t g = ((size_t)kvh * S + (kt + 1) * 64 + r) * HD + c8 * 8;
        pKh[it] = *(const ushort8*)&Kh[g];
        pKl[it] = *(const ushort8*)&Kl[g];
      }
#pragma unroll
      for (int it = 0; it < 4; ++it) {
        int idx = tid + it * 256;
        int d = idx >> 3, c8 = idx & 7;
        size_t g = ((size_t)kvh * HD + d) * S + (kt + 1) * 64 + c8 * 8;
        pV[it] = *(const ushort8*)&Vt[g];
      }
    }

    // S = Q K^T (split 3-term)
    f32x4 sc[4];
#pragma unroll
    for (int j = 0; j < 4; ++j) sc[j] = (f32x4){0.f, 0.f, 0.f, 0.f};
#pragma unroll
    for (int d4 = 0; d4 < 4; ++d4) {
#pragma unroll
      for (int j = 0; j < 4; ++j) {
        int b = (j * 16 + l16) * 136 + d4 * 32 + quad * 8;
        bf16x8 bh = *(bf16x8*)&sKh[b];
        bf16x8 bl = *(bf16x8*)&sKl[b];
        sc[j] = __builtin_amdgcn_mfma_f32_16x16x32_bf16(fqh[d4], bh, sc[j], 0, 0, 0);
        sc[j] = __builtin_amdgcn_mfma_f32_16x16x32_bf16(fqh[d4], bl, sc[j], 0, 0, 0);
        sc[j] = __builtin_amdgcn_mfma_f32_16x16x32_bf16(fql[d4], bh, sc[j], 0, 0, 0);
      }
    }
    const bool diag = (kt == qt);
#pragma unroll
    for (int j = 0; j < 4; ++j) {
      int col_l = j * 16 + l16;
#pragma unroll
      for (int r = 0; r < 4; ++r) {
        float v = sc[j][r] * SCALE;
        if (diag && col_l > row_l + r) v = -INFINITY;
        sc[j][r] = v;
      }
    }
    float tm[4];
#pragma unroll
    for (int r = 0; r < 4; ++r) {
      float t = sc[0][r];
#pragma unroll
      for (int j = 1; j < 4; ++j) t = fmaxf(t, sc[j][r]);
      tm[r] = t;
    }
#pragma unroll
    for (int off = 1; off < 16; off <<= 1)
#pragma unroll
      for (int r = 0; r < 4; ++r) tm[r] = fmaxf(tm[r], __shfl_xor(tm[r], off));
    float alpha[4];
#pragma unroll
    for (int r = 0; r < 4; ++r) {
      float mn = fmaxf(m_[r], tm[r]);
      alpha[r] = __expf(m_[r] - mn);
      m_[r] = mn;
    }
    float psum[4] = {0.f, 0.f, 0.f, 0.f};
#pragma unroll
    for (int j = 0; j < 4; ++j)
#pragma unroll
      for (int r = 0; r < 4; ++r) {
        float p = __expf(sc[j][r] - m_[r]);
        sc[j][r] = p;
        psum[r] += p;
      }
#pragma unroll
    for (int off = 1; off < 16; off <<= 1)
#pragma unroll
      for (int r = 0; r < 4; ++r) psum[r] += __shfl_xor(psum[r], off);
#pragma unroll
    for (int r = 0; r < 4; ++r) l_[r] = l_[r] * alpha[r] + psum[r];
#pragma unroll
    for (int jn = 0; jn < 8; ++jn)
#pragma unroll
      for (int r = 0; r < 4; ++r) O[jn][r] *= alpha[r];
#pragma unroll
    for (int j = 0; j < 4; ++j)
#pragma unroll
      for (int r = 0; r < 4; ++r)
        sP[wbase + (quad * 4 + r) * 72 + j * 16 + l16] = f2b(sc[j][r]);
    bf16x8 ap0 = *(bf16x8*)&sP[wbase + l16 * 72 + quad * 8];
    bf16x8 ap1 = *(bf16x8*)&sP[wbase + l16 * 72 + 32 + quad * 8];
#pragma unroll
    for (int jn = 0; jn < 8; ++jn) {
      bf16x8 bv0 = *(bf16x8*)&sVt[(jn * 16 + l16) * 72 + quad * 8];
      bf16x8 bv1 = *(bf16x8*)&sVt[(jn * 16 + l16) * 72 + 32 + quad * 8];
      O[jn] = __builtin_amdgcn_mfma_f32_16x16x32_bf16(ap0, bv0, O[jn], 0, 0, 0);
      O[jn] = __builtin_amdgcn_mfma_f32_16x16x32_bf16(ap1, bv1, O[jn], 0, 0, 0);
    }
  }
  float linv[4];
#pragma unroll
  for (int r = 0; r < 4; ++r) linv[r] = 1.0f / l_[r];
#pragma unroll
  for (int jn = 0; jn < 8; ++jn)
#pragma unroll
    for (int r = 0; r < 4; ++r)
      AOh[(size_t)(q0 + row_l + r) * NQ + h * HD + jn * 16 + l16] =
          f2b(O[jn][r] * linv[r]);
  if (l16 == 0) {
#pragma unroll
    for (int r = 0; r < 4; ++r) {
      mbuf[h * S + q0 + row_l + r] = m_[r];
      lbuf[h * S + q0 + row_l + r] = l_[r];
    }
  }
}

// ---------------------------------------------------------------------------
// MFMA cur pass. Flat 512-block grid with anti-diagonal (kt,h) remap:
// co-resident blocks do (32-kt)+(kt+1) = 33 q-tiles uniformly.
// kt extended to 0..31; tail writes land in cur[<S], topk reads only <SKEEP.
// ---------------------------------------------------------------------------
__global__ __launch_bounds__(256) void cur_mfma(
    const unsigned short* __restrict__ Qh, const unsigned short* __restrict__ Ql,
    const unsigned short* __restrict__ Kh, const unsigned short* __restrict__ Kl,
    const float* __restrict__ mbuf, const float* __restrict__ lbuf,
    float* __restrict__ cur) {
  const int x = blockIdx.x;
  const int base = x & 255;
  const int kt0 = base & 31, h0 = base >> 5;
  const int kt = (x < 256) ? kt0 : 31 - kt0;
  const int h  = (x < 256) ? h0 : h0 + 8;
  const int kvh = h / GROUPS;
  const int tid = threadIdx.x;
  const int lane = tid & 63, w = tid >> 6;
  const int quad = lane >> 4, l16 = lane & 15;

  __shared__ __align__(16) unsigned short sKh[8704];
  __shared__ __align__(16) unsigned short sKl[8704];
  __shared__ __align__(16) unsigned short sQh[8704];
  __shared__ __align__(16) unsigned short sQl[8704];
  __shared__ float smq[64], slinv[64];

#pragma unroll
  for (int it = 0; it < 4; ++it) {
    int idx = tid + it * 256;
    int r = idx >> 4, c8 = idx & 15;
    size_t g = ((size_t)kvh * S + kt * 64 + r) * HD + c8 * 8;
    int li = r * 136 + c8 * 8;
    *(ushort8*)&sKh[li] = *(const ushort8*)&Kh[g];
    *(ushort8*)&sKl[li] = *(const ushort8*)&Kl[g];
  }
  __syncthreads();
  bf16x8 fkh[4], fkl[4];
#pragma unroll
  for (int d4 = 0; d4 < 4; ++d4) {
    int a = (w * 16 + l16) * 136 + d4 * 32 + quad * 8;
    fkh[d4] = *(bf16x8*)&sKh[a];
    fkl[d4] = *(bf16x8*)&sKl[a];
  }

  const int krow_l = w * 16 + quad * 4;
  float csum[4] = {0.f, 0.f, 0.f, 0.f};

  ushort8 pQh[4], pQl[4];
  float pm = 0.f, pli = 0.f;
#pragma unroll
  for (int it = 0; it < 4; ++it) {
    int idx = tid + it * 256;
    int r = idx >> 4, c8 = idx & 15;
    size_t g = (size_t)(kt * 64 + r) * NQ + h * HD + c8 * 8;
    pQh[it] = *(const ushort8*)&Qh[g];
    pQl[it] = *(const ushort8*)&Ql[g];
  }
  if (tid < 64) {
    pm = mbuf[h * S + kt * 64 + tid];
    pli = 1.0f / lbuf[h * S + kt * 64 + tid];
  }

  for (int qt = kt; qt < S / 64; ++qt) {
    __syncthreads();
#pragma unroll
    for (int it = 0; it < 4; ++it) {
      int idx = tid + it * 256;
      int r = idx >> 4, c8 = idx & 15;
      int li = r * 136 + c8 * 8;
      *(ushort8*)&sQh[li] = pQh[it];
      *(ushort8*)&sQl[li] = pQl[it];
    }
    if (tid < 64) { smq[tid] = pm; slinv[tid] = pli; }
    __syncthreads();
    if (qt + 1 < S / 64) {
#pragma unroll
      for (int it = 0; it < 4; ++it) {
        int idx = tid + it * 256;
        int r = idx >> 4, c8 = idx & 15;
        size_t g = (size_t)((qt + 1) * 64 + r) * NQ + h * HD + c8 * 8;
        pQh[it] = *(const ushort8*)&Qh[g];
        pQl[it] = *(const ushort8*)&Ql[g];
      }
      if (tid < 64) {
        pm = mbuf[h * S + (qt + 1) * 64 + tid];
        pli = 1.0f / lbuf[h * S + (qt + 1) * 64 + tid];
      }
    }
    f32x4 sc[4];
#pragma unroll
    for (int j = 0; j < 4; ++j) sc[j] = (f32x4){0.f, 0.f, 0.f, 0.f};
#pragma unroll
    for (int d4 = 0; d4 < 4; ++d4) {
#pragma unroll
      for (int j = 0; j < 4; ++j) {
        int b = (j * 16 + l16) * 136 + d4 * 32 + quad * 8;
        bf16x8 bh = *(bf16x8*)&sQh[b];
        bf16x8 bl = *(bf16x8*)&sQl[b];
        sc[j] = __builtin_amdgcn_mfma_f32_16x16x32_bf16(fkh[d4], bh, sc[j], 0, 0, 0);
        sc[j] = __builtin_amdgcn_mfma_f32_16x16x32_bf16(fkh[d4], bl, sc[j], 0, 0, 0);
        sc[j] = __builtin_amdgcn_mfma_f32_16x16x32_bf16(fkl[d4], bh, sc[j], 0, 0, 0);
      }
    }
    const bool diag = (qt == kt);
#pragma unroll
    for (int j = 0; j < 4; ++j) {
      int qcol_l = j * 16 + l16;
      float mqv = smq[qcol_l];
      float lv = slinv[qcol_l];
#pragma unroll
      for (int r = 0; r < 4; ++r) {
        float p = __expf(sc[j][r] * SCALE - mqv) * lv;
        if (diag && (krow_l + r) > qcol_l) p = 0.f;
        csum[r] += p;
      }
    }
  }
#pragma unroll
  for (int off = 1; off < 16; off <<= 1)
#pragma unroll
    for (int r = 0; r < 4; ++r) csum[r] += __shfl_xor(csum[r], off);
  if (l16 == 0) {
#pragma unroll
    for (int r = 0; r < 4; ++r)
      cur[h * S + kt * 64 + krow_l + r] = csum[r];
  }
}

// ---------------------------------------------------------------------------
// top-k + mask (unchanged, verified)
// ---------------------------------------------------------------------------
__global__ __launch_bounds__(256) void topk_kernel(
    const float* __restrict__ cur, float* __restrict__ mask) {
  const int h = blockIdx.x;
  const int tid = threadIdx.x;
  __shared__ unsigned uv[SKEEP];
  __shared__ int red[256];

  for (int i = tid; i < SKEEP; i += 256) uv[i] = __float_as_uint(cur[h * S + i]);
  __syncthreads();

  unsigned lo = 0u, hi = 0xffffffffu;
  while (lo < hi) {
    unsigned mid = (unsigned)((((unsigned long long)lo + hi) + 1ull) >> 1);
    int c = 0;
    for (int i = tid; i < SKEEP; i += 256) c += (uv[i] >= mid) ? 1 : 0;
    red[tid] = c;
    __syncthreads();
    for (int s = 128; s > 0; s >>= 1) {
      if (tid < s) red[tid] += red[tid + s];
      __syncthreads();
    }
    int cnt = red[0];
    __syncthreads();
    if (cnt >= HEAVY) lo = mid; else hi = mid - 1;
  }
  const unsigned vk = lo;
  int c = 0;
  for (int i = tid; i < SKEEP; i += 256) c += (uv[i] > vk) ? 1 : 0;
  red[tid] = c;
  __syncthreads();
  for (int s = 128; s > 0; s >>= 1) {
    if (tid < s) red[tid] += red[tid + s];
    __syncthreads();
  }
  const int cgt = red[0];
  __syncthreads();
  const int r = HEAVY - cgt;

  for (int j = tid; j < MASKC; j += 256)
    mask[(size_t)h * MASKC + j] = (j >= MASKC - RECENT) ? 1.0f : 0.0f;
  __syncthreads();
  for (int i = tid; i < SKEEP; i += 256)
    if (uv[i] > vk) mask[(size_t)h * MASKC + i] = 1.0f;
  if (tid == 0) {
    int rem = r;
    for (int i = 0; i < SKEEP && rem > 0; ++i) {
      if (uv[i] == vk) { mask[(size_t)h * MASKC + i] = 1.0f; --rem; }
    }
  }
}

// ---------------------------------------------------------------------------
extern "C" void kernel_launch(void* const* d_in, const int* in_sizes, int n_in,
                              void* d_out, int out_size, void* d_ws,
                              size_t ws_size, hipStream_t stream) {
  const float* hs  = (const float*)d_in[0];
  const float* q_w = (const float*)d_in[1];
  const float* q_b = (const float*)d_in[2];
  const float* k_w = (const float*)d_in[3];
  const float* k_b = (const float*)d_in[4];
  const float* v_w = (const float*)d_in[5];
  const float* v_b = (const float*)d_in[6];
  const float* o_w = (const float*)d_in[7];

  char* ws = (char*)d_ws;
  unsigned short* Qh   = (unsigned short*)(ws + 0);
  unsigned short* Ql   = (unsigned short*)(ws + 8388608);
  unsigned short* Kh   = (unsigned short*)(ws + 16777216);
  unsigned short* Kl   = (unsigned short*)(ws + 18874368);
  unsigned short* Vrow = (unsigned short*)(ws + 20971520);
  unsigned short* Vt   = (unsigned short*)(ws + 23068672);
  unsigned short* AOh  = (unsigned short*)(ws + 25165824);
  float* mb   = (float*)(ws + 33554432);
  float* lb   = (float*)(ws + 33685504);
  float* cur  = (float*)(ws + 33816576);
  float* bcat = (float*)(ws + 33947648);
  char* pool = ws + 33959936;
  unsigned short* hsh = (unsigned short*)pool;
  unsigned short* hsl = (unsigned short*)(pool + 8388608);
  unsigned short* WTh = (unsigned short*)(pool + 16777216);
  unsigned short* WTl = (unsigned short*)(pool + 29360128);
  unsigned short* OTh = (unsigned short*)pool;  // alias hsh (dead after gemm_qkv)

  float* outp  = (float*)d_out;
  float* maskp = outp + (size_t)S * D;

  dim3 blk(256);
  split_act<<<dim3(2048), blk, 0, stream>>>(hs, hsh, hsl, S * D);
  split_wT<<<dim3(NQ / 64, D / 64), blk, 0, stream>>>(q_w, WTh, WTl, D, NQ, 0, D);
  split_wT<<<dim3(NKV / 64, D / 64), blk, 0, stream>>>(k_w, WTh, WTl, D, NKV, NQ, D);
  split_wT<<<dim3(NKV / 64, D / 64), blk, 0, stream>>>(v_w, WTh, WTl, D, NKV, NQ + NKV, D);
  concat_bias<<<dim3((N3 + 255) / 256), blk, 0, stream>>>(q_b, k_b, v_b, bcat);
  gemm_qkv<<<dim3(N3 / 128, S / 128), blk, 0, stream>>>(
      hsh, hsl, WTh, WTl, bcat, Qh, Ql, Kh, Kl, Vrow, S, N3, D);
  prep_vt<<<dim3(S / 64, KVH), blk, 0, stream>>>(Vrow, Vt);
  wT_bf16<<<dim3(D / 64, NQ / 64), blk, 0, stream>>>(o_w, OTh, NQ, D);
  attn_mfma<<<dim3(512), blk, 0, stream>>>(Qh, Ql, Kh, Kl, Vt, AOh, mb, lb);
  cur_mfma<<<dim3(512), blk, 0, stream>>>(Qh, Ql, Kh, Kl, mb, lb, cur);
  topk_kernel<<<dim3(H), blk, 0, stream>>>(cur, maskp);
  gemm_bf16<<<dim3(D / 128, S / 128), blk, 0, stream>>>(AOh, OTh, outp, S, D, NQ);
}

// Round 7
// 428.310 us; speedup vs baseline: 12.5780x; 1.0744x over previous
//
#include <hip/hip_runtime.h>
#include <hip/hip_bf16.h>
#include <math.h>

// Problem constants
constexpr int S   = 2048;
constexpr int D   = 2048;
constexpr int H   = 16;
constexpr int KVH = 4;
constexpr int HD  = 128;
constexpr int NQ  = H * HD;      // 2048
constexpr int NKV = KVH * HD;    // 512
constexpr int N3  = NQ + 2 * NKV; // 3072
constexpr int GROUPS = H / KVH;   // 4
constexpr float SCALE = 0.088388347648318447f; // 128^-0.5
constexpr int HEAVY  = 204;
constexpr int RECENT = 204;
constexpr int SKEEP  = S - RECENT;  // 1844
constexpr int MASKC  = S + 1;       // 2049

typedef short bf16x8 __attribute__((ext_vector_type(8)));
typedef unsigned short ushort8 __attribute__((ext_vector_type(8)));
typedef unsigned short ushort4v __attribute__((ext_vector_type(4)));
typedef float f32x4 __attribute__((ext_vector_type(4)));

__device__ __forceinline__ unsigned short f2b(float x) {
  __hip_bfloat16 h = __float2bfloat16(x);
  return *(unsigned short*)&h;
}
__device__ __forceinline__ float b2f(unsigned short u) {
  __hip_bfloat16 h = *(__hip_bfloat16*)&u;
  return __bfloat162float(h);
}

// async global -> LDS, 16B per lane; LDS dest = wave-uniform base + lane*16
__device__ __forceinline__ void gload16(const unsigned short* g,
                                        unsigned short* l) {
  __builtin_amdgcn_global_load_lds(
      (const __attribute__((address_space(1))) unsigned int*)g,
      (__attribute__((address_space(3))) unsigned int*)l, 16, 0, 0);
}

// ---------------------------------------------------------------------------
// prep_all: one launch for all input preprocessing.
//  blocks [0,1024)    : split_wT(q_w)  -> WT rows [0,2048)
//  blocks [1024,1280) : split_wT(k_w)  -> WT rows [2048,2560)
//  blocks [1280,1536) : split_wT(v_w)  -> WT rows [2560,3072)
//  blocks [1536,2560) : wT_bf16(o_w)   -> OTh
//  blocks [2560,3072) : split_act(hs)  -> hsh/hsl
//  blocks [3072,3084) : concat bias    -> bcat
// ---------------------------------------------------------------------------
__device__ __forceinline__ void split_wT_dev(
    const float* __restrict__ in, unsigned short* __restrict__ oh,
    unsigned short* __restrict__ ol, int K, int N, int rowOff, int ldOut,
    int bx, int by, float (*Lt)[65]) {
  const int n0 = bx * 64, k0 = by * 64;
  const int t = threadIdx.x;
  const int cq = t & 15, r4 = t >> 4;
#pragma unroll
  for (int i = 0; i < 4; ++i) {
    int r = r4 + i * 16;
    float4 v = *(const float4*)&in[(size_t)(k0 + r) * N + n0 + cq * 4];
    Lt[cq * 4 + 0][r] = v.x;
    Lt[cq * 4 + 1][r] = v.y;
    Lt[cq * 4 + 2][r] = v.z;
    Lt[cq * 4 + 3][r] = v.w;
  }
  __syncthreads();
#pragma unroll
  for (int i = 0; i < 4; ++i) {
    int rr = r4 + i * 16;
    size_t base = (size_t)(rowOff + n0 + rr) * ldOut + k0 + cq * 4;
#pragma unroll
    for (int j = 0; j < 4; ++j) {
      float x = Lt[rr][cq * 4 + j];
      unsigned short h = f2b(x);
      oh[base + j] = h;
      ol[base + j] = f2b(x - b2f(h));
    }
  }
}

__global__ __launch_bounds__(256) void prep_all(
    const float* __restrict__ hs, const float* __restrict__ q_w,
    const float* __restrict__ k_w, const float* __restrict__ v_w,
    const float* __restrict__ o_w, const float* __restrict__ qb,
    const float* __restrict__ kb, const float* __restrict__ vb,
    unsigned short* __restrict__ hsh, unsigned short* __restrict__ hsl,
    unsigned short* __restrict__ WTh, unsigned short* __restrict__ WTl,
    unsigned short* __restrict__ OTh, float* __restrict__ bcat) {
  __shared__ float Lt[64][65];
  const int b = blockIdx.x;
  if (b < 1024) {
    split_wT_dev(q_w, WTh, WTl, D, NQ, 0, D, b & 31, b >> 5, Lt);
  } else if (b < 1280) {
    int b2 = b - 1024;
    split_wT_dev(k_w, WTh, WTl, D, NKV, NQ, D, b2 & 7, b2 >> 3, Lt);
  } else if (b < 1536) {
    int b2 = b - 1280;
    split_wT_dev(v_w, WTh, WTl, D, NKV, NQ + NKV, D, b2 & 7, b2 >> 3, Lt);
  } else if (b < 2560) {
    int b2 = b - 1536;
    const int n0 = (b2 & 31) * 64, k0 = (b2 >> 5) * 64;
    const int t = threadIdx.x;
    const int cq = t & 15, r4 = t >> 4;
#pragma unroll
    for (int i = 0; i < 4; ++i) {
      int r = r4 + i * 16;
      float4 v = *(const float4*)&o_w[(size_t)(k0 + r) * D + n0 + cq * 4];
      Lt[cq * 4 + 0][r] = v.x;
      Lt[cq * 4 + 1][r] = v.y;
      Lt[cq * 4 + 2][r] = v.z;
      Lt[cq * 4 + 3][r] = v.w;
    }
    __syncthreads();
#pragma unroll
    for (int i = 0; i < 4; ++i) {
      int rr = r4 + i * 16;
      size_t base = (size_t)(n0 + rr) * NQ + k0 + cq * 4;
#pragma unroll
      for (int j = 0; j < 4; ++j) OTh[base + j] = f2b(Lt[rr][cq * 4 + j]);
    }
  } else if (b < 3072) {
    int b2 = b - 2560;
    size_t base = (size_t)b2 * 8192;
    for (int i = threadIdx.x * 4; i < 8192; i += 1024) {
      float4 v = *(const float4*)&hs[base + i];
      ushort4v hv, lv;
      float xs[4] = {v.x, v.y, v.z, v.w};
#pragma unroll
      for (int j = 0; j < 4; ++j) {
        unsigned short h = f2b(xs[j]);
        hv[j] = h;
        lv[j] = f2b(xs[j] - b2f(h));
      }
      *(ushort4v*)&hsh[base + i] = hv;
      *(ushort4v*)&hsl[base + i] = lv;
    }
  } else {
    int i = (b - 3072) * 256 + threadIdx.x;
    if (i < NQ) bcat[i] = qb[i];
    else if (i < NQ + NKV) bcat[i] = kb[i - NQ];
    else if (i < N3) bcat[i] = vb[i - NQ - NKV];
  }
}

// ---------------------------------------------------------------------------
// QKV GEMM (split-bf16, 3 MFMA) with global_load_lds staging (XOR-swizzled
// 16B chunks: physical sub = logical chunk ^ (row&3)) and fused epilogue
// writing Qh/Ql, Kh/Kl ([kvh][S][HD]) and Vt ([kvh][HD][S]) directly.
// ---------------------------------------------------------------------------
__global__ __launch_bounds__(256) void gemm_qkv(
    const unsigned short* __restrict__ Ah, const unsigned short* __restrict__ Al,
    const unsigned short* __restrict__ Bh, const unsigned short* __restrict__ Bl,
    const float* __restrict__ bias,
    unsigned short* __restrict__ Qh, unsigned short* __restrict__ Ql,
    unsigned short* __restrict__ Kh, unsigned short* __restrict__ Kl,
    unsigned short* __restrict__ Vt, int M, int N, int K) {
  __shared__ __align__(16) unsigned short sAh[128 * 32];
  __shared__ __align__(16) unsigned short sAl[128 * 32];
  __shared__ __align__(16) unsigned short sBh[128 * 32];
  __shared__ __align__(16) unsigned short sBl[128 * 32];
  const int tid = threadIdx.x;
  const int lane = tid & 63, wave = tid >> 6;
  const int wm = wave >> 1, wn = wave & 1;
  const int quad = lane >> 4, l16 = lane & 15;
  const int m0 = blockIdx.y * 128, n0 = blockIdx.x * 128;

  // staging geometry: chunk c = wave*2+it covers rows [16c,16c+16);
  // lane l -> row 16c + (l>>2), physical sub l&3, global chunk (l&3)^((l>>2)&3)
  const int lr = lane >> 2;
  const int gj = (lane & 3) ^ (lr & 3);

  f32x4 acc[4][4];
#pragma unroll
  for (int i = 0; i < 4; ++i)
#pragma unroll
    for (int j = 0; j < 4; ++j) acc[i][j] = (f32x4){0.f, 0.f, 0.f, 0.f};

  for (int k0 = 0; k0 < K; k0 += 32) {
    __syncthreads();  // previous iteration's frag reads complete
#pragma unroll
    for (int it = 0; it < 2; ++it) {
      int c = wave * 2 + it;
      int r = c * 16 + lr;
      size_t ga = (size_t)(m0 + r) * K + k0 + gj * 8;
      size_t gb = (size_t)(n0 + r) * K + k0 + gj * 8;
      gload16(&Ah[ga], &sAh[c * 512]);
      gload16(&Al[ga], &sAl[c * 512]);
      gload16(&Bh[gb], &sBh[c * 512]);
      gload16(&Bl[gb], &sBl[c * 512]);
    }
    __syncthreads();  // drains vmcnt -> LDS ready
    const int sw = (quad ^ (l16 & 3)) * 8;
    bf16x8 fah[4], fal[4], fbh[4], fbl[4];
#pragma unroll
    for (int i = 0; i < 4; ++i) {
      int ra = (wm * 64 + i * 16 + l16) * 32 + sw;
      fah[i] = *(bf16x8*)&sAh[ra];
      fal[i] = *(bf16x8*)&sAl[ra];
      int rb = (wn * 64 + i * 16 + l16) * 32 + sw;
      fbh[i] = *(bf16x8*)&sBh[rb];
      fbl[i] = *(bf16x8*)&sBl[rb];
    }
#pragma unroll
    for (int i = 0; i < 4; ++i)
#pragma unroll
      for (int j = 0; j < 4; ++j) {
        acc[i][j] = __builtin_amdgcn_mfma_f32_16x16x32_bf16(fah[i], fbh[j], acc[i][j], 0, 0, 0);
        acc[i][j] = __builtin_amdgcn_mfma_f32_16x16x32_bf16(fah[i], fbl[j], acc[i][j], 0, 0, 0);
        acc[i][j] = __builtin_amdgcn_mfma_f32_16x16x32_bf16(fal[i], fbh[j], acc[i][j], 0, 0, 0);
      }
  }
#pragma unroll
  for (int i = 0; i < 4; ++i) {
#pragma unroll
    for (int j = 0; j < 4; ++j) {
      int row = m0 + wm * 64 + i * 16 + quad * 4;
      int col = n0 + wn * 64 + j * 16 + l16;
      float bv = bias[col];
      if (n0 < NQ) {
#pragma unroll
        for (int r = 0; r < 4; ++r) {
          float x = acc[i][j][r] + bv;
          unsigned short hb = f2b(x);
          size_t o = (size_t)(row + r) * NQ + col;
          Qh[o] = hb;
          Ql[o] = f2b(x - b2f(hb));
        }
      } else if (n0 < NQ + NKV) {
        int c = col - NQ;
        size_t ob = ((size_t)(c >> 7) * S) * HD + (c & 127);
#pragma unroll
        for (int r = 0; r < 4; ++r) {
          float x = acc[i][j][r] + bv;
          unsigned short hb = f2b(x);
          size_t o = ob + (size_t)(row + r) * HD;
          Kh[o] = hb;
          Kl[o] = f2b(x - b2f(hb));
        }
      } else {
        int c = col - NQ - NKV;
        ushort4v pv;
#pragma unroll
        for (int r = 0; r < 4; ++r) pv[r] = f2b(acc[i][j][r] + bv);
        *(ushort4v*)&Vt[((size_t)(c >> 7) * HD + (c & 127)) * S + row] = pv;
      }
    }
  }
}

// ---------------------------------------------------------------------------
// Plain bf16 GEMM (oproj) with global_load_lds staging, same swizzle.
// ---------------------------------------------------------------------------
__global__ __launch_bounds__(256) void gemm_bf16(
    const unsigned short* __restrict__ Ah, const unsigned short* __restrict__ Bh,
    float* __restrict__ C, int M, int N, int K) {
  __shared__ __align__(16) unsigned short sA[128 * 32];
  __shared__ __align__(16) unsigned short sB[128 * 32];
  const int tid = threadIdx.x;
  const int lane = tid & 63, wave = tid >> 6;
  const int wm = wave >> 1, wn = wave & 1;
  const int quad = lane >> 4, l16 = lane & 15;
  const int m0 = blockIdx.y * 128, n0 = blockIdx.x * 128;
  const int lr = lane >> 2;
  const int gj = (lane & 3) ^ (lr & 3);

  f32x4 acc[4][4];
#pragma unroll
  for (int i = 0; i < 4; ++i)
#pragma unroll
    for (int j = 0; j < 4; ++j) acc[i][j] = (f32x4){0.f, 0.f, 0.f, 0.f};

  for (int k0 = 0; k0 < K; k0 += 32) {
    __syncthreads();
#pragma unroll
    for (int it = 0; it < 2; ++it) {
      int c = wave * 2 + it;
      int r = c * 16 + lr;
      size_t ga = (size_t)(m0 + r) * K + k0 + gj * 8;
      size_t gb = (size_t)(n0 + r) * K + k0 + gj * 8;
      gload16(&Ah[ga], &sA[c * 512]);
      gload16(&Bh[gb], &sB[c * 512]);
    }
    __syncthreads();
    const int sw = (quad ^ (l16 & 3)) * 8;
    bf16x8 fa[4], fb[4];
#pragma unroll
    for (int i = 0; i < 4; ++i) {
      fa[i] = *(bf16x8*)&sA[(wm * 64 + i * 16 + l16) * 32 + sw];
      fb[i] = *(bf16x8*)&sB[(wn * 64 + i * 16 + l16) * 32 + sw];
    }
#pragma unroll
    for (int i = 0; i < 4; ++i)
#pragma unroll
      for (int j = 0; j < 4; ++j)
        acc[i][j] = __builtin_amdgcn_mfma_f32_16x16x32_bf16(fa[i], fb[j], acc[i][j], 0, 0, 0);
  }
#pragma unroll
  for (int i = 0; i < 4; ++i)
#pragma unroll
    for (int j = 0; j < 4; ++j) {
      int row = m0 + wm * 64 + i * 16 + quad * 4;
      int col = n0 + wn * 64 + j * 16 + l16;
#pragma unroll
      for (int r = 0; r < 4; ++r)
        C[(size_t)(row + r) * N + col] = acc[i][j][r];
    }
}

// ---------------------------------------------------------------------------
// MFMA flash attention (unchanged from R6: anti-diagonal remap + reg prefetch)
// ---------------------------------------------------------------------------
__global__ __launch_bounds__(256) void attn_mfma(
    const unsigned short* __restrict__ Qh, const unsigned short* __restrict__ Ql,
    const unsigned short* __restrict__ Kh, const unsigned short* __restrict__ Kl,
    const unsigned short* __restrict__ Vt, unsigned short* __restrict__ AOh,
    float* __restrict__ mbuf, float* __restrict__ lbuf) {
  const int x = blockIdx.x;
  const int base = x & 255;
  const int qt0 = base & 31, h0 = base >> 5;
  const int qt = (x < 256) ? qt0 : 31 - qt0;
  const int h  = (x < 256) ? h0 : h0 + 8;
  const int kvh = h / GROUPS;
  const int tid = threadIdx.x;
  const int lane = tid & 63, w = tid >> 6;
  const int quad = lane >> 4, l16 = lane & 15;
  const int q0 = qt * 64;

  __shared__ __align__(16) unsigned short smem[31232];  // 62464 B
  unsigned short* sQh = smem;
  unsigned short* sQl = smem + 8704;
  unsigned short* sKh = smem;             // reuse after Q frags read
  unsigned short* sKl = smem + 8704;
  unsigned short* sVt = smem + 17408;     // 128 x 72
  unsigned short* sP  = smem + 26624;     // 4 waves x 16 x 72

  ushort8 pKh[4], pKl[4], pV[4];
#pragma unroll
  for (int it = 0; it < 4; ++it) {
    int idx = tid + it * 256;
    int r = idx >> 4, c8 = idx & 15;
    size_t g = ((size_t)kvh * S + r) * HD + c8 * 8;
    pKh[it] = *(const ushort8*)&Kh[g];
    pKl[it] = *(const ushort8*)&Kl[g];
  }
#pragma unroll
  for (int it = 0; it < 4; ++it) {
    int idx = tid + it * 256;
    int d = idx >> 3, c8 = idx & 7;
    size_t g = ((size_t)kvh * HD + d) * S + c8 * 8;
    pV[it] = *(const ushort8*)&Vt[g];
  }

#pragma unroll
  for (int it = 0; it < 4; ++it) {
    int idx = tid + it * 256;
    int r = idx >> 4, c8 = idx & 15;
    size_t g = (size_t)(q0 + r) * NQ + h * HD + c8 * 8;
    int li = r * 136 + c8 * 8;
    *(ushort8*)&sQh[li] = *(const ushort8*)&Qh[g];
    *(ushort8*)&sQl[li] = *(const ushort8*)&Ql[g];
  }
  __syncthreads();
  bf16x8 fqh[4], fql[4];
#pragma unroll
  for (int d4 = 0; d4 < 4; ++d4) {
    int a = (w * 16 + l16) * 136 + d4 * 32 + quad * 8;
    fqh[d4] = *(bf16x8*)&sQh[a];
    fql[d4] = *(bf16x8*)&sQl[a];
  }

  f32x4 O[8];
#pragma unroll
  for (int jn = 0; jn < 8; ++jn) O[jn] = (f32x4){0.f, 0.f, 0.f, 0.f};
  float m_[4], l_[4];
#pragma unroll
  for (int r = 0; r < 4; ++r) { m_[r] = -INFINITY; l_[r] = 0.f; }

  const int row_l = w * 16 + quad * 4;
  const int wbase = w * 1152;

  for (int kt = 0; kt <= qt; ++kt) {
    __syncthreads();
#pragma unroll
    for (int it = 0; it < 4; ++it) {
      int idx = tid + it * 256;
      int r = idx >> 4, c8 = idx & 15;
      *(ushort8*)&sKh[r * 136 + c8 * 8] = pKh[it];
      *(ushort8*)&sKl[r * 136 + c8 * 8] = pKl[it];
    }
#pragma unroll
    for (int it = 0; it < 4; ++it) {
      int idx = tid + it * 256;
      int d = idx >> 3, c8 = idx & 7;
      *(ushort8*)&sVt[d * 72 + c8 * 8] = pV[it];
    }
    __syncthreads();
    if (kt < qt) {
#pragma unroll
      for (int it = 0; it < 4; ++it) {
        int idx = tid + it * 256;
        int r = idx >> 4, c8 = idx & 15;
        size_t g = ((size_t)kvh * S + (kt + 1) * 64 + r) * HD + c8 * 8;
        pKh[it] = *(const ushort8*)&Kh[g];
        pKl[it] = *(const ushort8*)&Kl[g];
      }
#pragma unroll
      for (int it = 0; it < 4; ++it) {
        int idx = tid + it * 256;
        int d = idx >> 3, c8 = idx & 7;
        size_t g = ((size_t)kvh * HD + d) * S + (kt + 1) * 64 + c8 * 8;
        pV[it] = *(const ushort8*)&Vt[g];
      }
    }

    f32x4 sc[4];
#pragma unroll
    for (int j = 0; j < 4; ++j) sc[j] = (f32x4){0.f, 0.f, 0.f, 0.f};
#pragma unroll
    for (int d4 = 0; d4 < 4; ++d4) {
#pragma unroll
      for (int j = 0; j < 4; ++j) {
        int b = (j * 16 + l16) * 136 + d4 * 32 + quad * 8;
        bf16x8 bh = *(bf16x8*)&sKh[b];
        bf16x8 bl = *(bf16x8*)&sKl[b];
        sc[j] = __builtin_amdgcn_mfma_f32_16x16x32_bf16(fqh[d4], bh, sc[j], 0, 0, 0);
        sc[j] = __builtin_amdgcn_mfma_f32_16x16x32_bf16(fqh[d4], bl, sc[j], 0, 0, 0);
        sc[j] = __builtin_amdgcn_mfma_f32_16x16x32_bf16(fql[d4], bh, sc[j], 0, 0, 0);
      }
    }
    const bool diag = (kt == qt);
#pragma unroll
    for (int j = 0; j < 4; ++j) {
      int col_l = j * 16 + l16;
#pragma unroll
      for (int r = 0; r < 4; ++r) {
        float v = sc[j][r] * SCALE;
        if (diag && col_l > row_l + r) v = -INFINITY;
        sc[j][r] = v;
      }
    }
    float tm[4];
#pragma unroll
    for (int r = 0; r < 4; ++r) {
      float t = sc[0][r];
#pragma unroll
      for (int j = 1; j < 4; ++j) t = fmaxf(t, sc[j][r]);
      tm[r] = t;
    }
#pragma unroll
    for (int off = 1; off < 16; off <<= 1)
#pragma unroll
      for (int r = 0; r < 4; ++r) tm[r] = fmaxf(tm[r], __shfl_xor(tm[r], off));
    float alpha[4];
#pragma unroll
    for (int r = 0; r < 4; ++r) {
      float mn = fmaxf(m_[r], tm[r]);
      alpha[r] = __expf(m_[r] - mn);
      m_[r] = mn;
    }
    float psum[4] = {0.f, 0.f, 0.f, 0.f};
#pragma unroll
    for (int j = 0; j < 4; ++j)
#pragma unroll
      for (int r = 0; r < 4; ++r) {
        float p = __expf(sc[j][r] - m_[r]);
        sc[j][r] = p;
        psum[r] += p;
      }
#pragma unroll
    for (int off = 1; off < 16; off <<= 1)
#pragma unroll
      for (int r = 0; r < 4; ++r) psum[r] += __shfl_xor(psum[r], off);
#pragma unroll
    for (int r = 0; r < 4; ++r) l_[r] = l_[r] * alpha[r] + psum[r];
#pragma unroll
    for (int jn = 0; jn < 8; ++jn)
#pragma unroll
      for (int r = 0; r < 4; ++r) O[jn][r] *= alpha[r];
#pragma unroll
    for (int j = 0; j < 4; ++j)
#pragma unroll
      for (int r = 0; r < 4; ++r)
        sP[wbase + (quad * 4 + r) * 72 + j * 16 + l16] = f2b(sc[j][r]);
    bf16x8 ap0 = *(bf16x8*)&sP[wbase + l16 * 72 + quad * 8];
    bf16x8 ap1 = *(bf16x8*)&sP[wbase + l16 * 72 + 32 + quad * 8];
#pragma unroll
    for (int jn = 0; jn < 8; ++jn) {
      bf16x8 bv0 = *(bf16x8*)&sVt[(jn * 16 + l16) * 72 + quad * 8];
      bf16x8 bv1 = *(bf16x8*)&sVt[(jn * 16 + l16) * 72 + 32 + quad * 8];
      O[jn] = __builtin_amdgcn_mfma_f32_16x16x32_bf16(ap0, bv0, O[jn], 0, 0, 0);
      O[jn] = __builtin_amdgcn_mfma_f32_16x16x32_bf16(ap1, bv1, O[jn], 0, 0, 0);
    }
  }
  float linv[4];
#pragma unroll
  for (int r = 0; r < 4; ++r) linv[r] = 1.0f / l_[r];
#pragma unroll
  for (int jn = 0; jn < 8; ++jn)
#pragma unroll
    for (int r = 0; r < 4; ++r)
      AOh[(size_t)(q0 + row_l + r) * NQ + h * HD + jn * 16 + l16] =
          f2b(O[jn][r] * linv[r]);
  if (l16 == 0) {
#pragma unroll
    for (int r = 0; r < 4; ++r) {
      mbuf[h * S + q0 + row_l + r] = m_[r];
      lbuf[h * S + q0 + row_l + r] = l_[r];
    }
  }
}

// ---------------------------------------------------------------------------
// MFMA cur pass (unchanged from R6)
// ---------------------------------------------------------------------------
__global__ __launch_bounds__(256) void cur_mfma(
    const unsigned short* __restrict__ Qh, const unsigned short* __restrict__ Ql,
    const unsigned short* __restrict__ Kh, const unsigned short* __restrict__ Kl,
    const float* __restrict__ mbuf, const float* __restrict__ lbuf,
    float* __restrict__ cur) {
  const int x = blockIdx.x;
  const int base = x & 255;
  const int kt0 = base & 31, h0 = base >> 5;
  const int kt = (x < 256) ? kt0 : 31 - kt0;
  const int h  = (x < 256) ? h0 : h0 + 8;
  const int kvh = h / GROUPS;
  const int tid = threadIdx.x;
  const int lane = tid & 63, w = tid >> 6;
  const int quad = lane >> 4, l16 = lane & 15;

  __shared__ __align__(16) unsigned short sKh[8704];
  __shared__ __align__(16) unsigned short sKl[8704];
  __shared__ __align__(16) unsigned short sQh[8704];
  __shared__ __align__(16) unsigned short sQl[8704];
  __shared__ float smq[64], slinv[64];

#pragma unroll
  for (int it = 0; it < 4; ++it) {
    int idx = tid + it * 256;
    int r = idx >> 4, c8 = idx & 15;
    size_t g = ((size_t)kvh * S + kt * 64 + r) * HD + c8 * 8;
    int li = r * 136 + c8 * 8;
    *(ushort8*)&sKh[li] = *(const ushort8*)&Kh[g];
    *(ushort8*)&sKl[li] = *(const ushort8*)&Kl[g];
  }
  __syncthreads();
  bf16x8 fkh[4], fkl[4];
#pragma unroll
  for (int d4 = 0; d4 < 4; ++d4) {
    int a = (w * 16 + l16) * 136 + d4 * 32 + quad * 8;
    fkh[d4] = *(bf16x8*)&sKh[a];
    fkl[d4] = *(bf16x8*)&sKl[a];
  }

  const int krow_l = w * 16 + quad * 4;
  float csum[4] = {0.f, 0.f, 0.f, 0.f};

  ushort8 pQh[4], pQl[4];
  float pm = 0.f, pli = 0.f;
#pragma unroll
  for (int it = 0; it < 4; ++it) {
    int idx = tid + it * 256;
    int r = idx >> 4, c8 = idx & 15;
    size_t g = (size_t)(kt * 64 + r) * NQ + h * HD + c8 * 8;
    pQh[it] = *(const ushort8*)&Qh[g];
    pQl[it] = *(const ushort8*)&Ql[g];
  }
  if (tid < 64) {
    pm = mbuf[h * S + kt * 64 + tid];
    pli = 1.0f / lbuf[h * S + kt * 64 + tid];
  }

  for (int qt = kt; qt < S / 64; ++qt) {
    __syncthreads();
#pragma unroll
    for (int it = 0; it < 4; ++it) {
      int idx = tid + it * 256;
      int r = idx >> 4, c8 = idx & 15;
      int li = r * 136 + c8 * 8;
      *(ushort8*)&sQh[li] = pQh[it];
      *(ushort8*)&sQl[li] = pQl[it];
    }
    if (tid < 64) { smq[tid] = pm; slinv[tid] = pli; }
    __syncthreads();
    if (qt + 1 < S / 64) {
#pragma unroll
      for (int it = 0; it < 4; ++it) {
        int idx = tid + it * 256;
        int r = idx >> 4, c8 = idx & 15;
        size_t g = (size_t)((qt + 1) * 64 + r) * NQ + h * HD + c8 * 8;
        pQh[it] = *(const ushort8*)&Qh[g];
        pQl[it] = *(const ushort8*)&Ql[g];
      }
      if (tid < 64) {
        pm = mbuf[h * S + (qt + 1) * 64 + tid];
        pli = 1.0f / lbuf[h * S + (qt + 1) * 64 + tid];
      }
    }
    f32x4 sc[4];
#pragma unroll
    for (int j = 0; j < 4; ++j) sc[j] = (f32x4){0.f, 0.f, 0.f, 0.f};
#pragma unroll
    for (int d4 = 0; d4 < 4; ++d4) {
#pragma unroll
      for (int j = 0; j < 4; ++j) {
        int b = (j * 16 + l16) * 136 + d4 * 32 + quad * 8;
        bf16x8 bh = *(bf16x8*)&sQh[b];
        bf16x8 bl = *(bf16x8*)&sQl[b];
        sc[j] = __builtin_amdgcn_mfma_f32_16x16x32_bf16(fkh[d4], bh, sc[j], 0, 0, 0);
        sc[j] = __builtin_amdgcn_mfma_f32_16x16x32_bf16(fkh[d4], bl, sc[j], 0, 0, 0);
        sc[j] = __builtin_amdgcn_mfma_f32_16x16x32_bf16(fkl[d4], bh, sc[j], 0, 0, 0);
      }
    }
    const bool diag = (qt == kt);
#pragma unroll
    for (int j = 0; j < 4; ++j) {
      int qcol_l = j * 16 + l16;
      float mqv = smq[qcol_l];
      float lv = slinv[qcol_l];
#pragma unroll
      for (int r = 0; r < 4; ++r) {
        float p = __expf(sc[j][r] * SCALE - mqv) * lv;
        if (diag && (krow_l + r) > qcol_l) p = 0.f;
        csum[r] += p;
      }
    }
  }
#pragma unroll
  for (int off = 1; off < 16; off <<= 1)
#pragma unroll
    for (int r = 0; r < 4; ++r) csum[r] += __shfl_xor(csum[r], off);
  if (l16 == 0) {
#pragma unroll
    for (int r = 0; r < 4; ++r)
      cur[h * S + kt * 64 + krow_l + r] = csum[r];
  }
}

// ---------------------------------------------------------------------------
// top-k + mask (unchanged, verified)
// ---------------------------------------------------------------------------
__global__ __launch_bounds__(256) void topk_kernel(
    const float* __restrict__ cur, float* __restrict__ mask) {
  const int h = blockIdx.x;
  const int tid = threadIdx.x;
  __shared__ unsigned uv[SKEEP];
  __shared__ int red[256];

  for (int i = tid; i < SKEEP; i += 256) uv[i] = __float_as_uint(cur[h * S + i]);
  __syncthreads();

  unsigned lo = 0u, hi = 0xffffffffu;
  while (lo < hi) {
    unsigned mid = (unsigned)((((unsigned long long)lo + hi) + 1ull) >> 1);
    int c = 0;
    for (int i = tid; i < SKEEP; i += 256) c += (uv[i] >= mid) ? 1 : 0;
    red[tid] = c;
    __syncthreads();
    for (int s = 128; s > 0; s >>= 1) {
      if (tid < s) red[tid] += red[tid + s];
      __syncthreads();
    }
    int cnt = red[0];
    __syncthreads();
    if (cnt >= HEAVY) lo = mid; else hi = mid - 1;
  }
  const unsigned vk = lo;
  int c = 0;
  for (int i = tid; i < SKEEP; i += 256) c += (uv[i] > vk) ? 1 : 0;
  red[tid] = c;
  __syncthreads();
  for (int s = 128; s > 0; s >>= 1) {
    if (tid < s) red[tid] += red[tid + s];
    __syncthreads();
  }
  const int cgt = red[0];
  __syncthreads();
  const int r = HEAVY - cgt;

  for (int j = tid; j < MASKC; j += 256)
    mask[(size_t)h * MASKC + j] = (j >= MASKC - RECENT) ? 1.0f : 0.0f;
  __syncthreads();
  for (int i = tid; i < SKEEP; i += 256)
    if (uv[i] > vk) mask[(size_t)h * MASKC + i] = 1.0f;
  if (tid == 0) {
    int rem = r;
    for (int i = 0; i < SKEEP && rem > 0; ++i) {
      if (uv[i] == vk) { mask[(size_t)h * MASKC + i] = 1.0f; --rem; }
    }
  }
}

// ---------------------------------------------------------------------------
extern "C" void kernel_launch(void* const* d_in, const int* in_sizes, int n_in,
                              void* d_out, int out_size, void* d_ws,
                              size_t ws_size, hipStream_t stream) {
  const float* hs  = (const float*)d_in[0];
  const float* q_w = (const float*)d_in[1];
  const float* q_b = (const float*)d_in[2];
  const float* k_w = (const float*)d_in[3];
  const float* k_b = (const float*)d_in[4];
  const float* v_w = (const float*)d_in[5];
  const float* v_b = (const float*)d_in[6];
  const float* o_w = (const float*)d_in[7];

  char* ws = (char*)d_ws;
  unsigned short* Qh   = (unsigned short*)(ws + 0);
  unsigned short* Ql   = (unsigned short*)(ws + 8388608);
  unsigned short* Kh   = (unsigned short*)(ws + 16777216);
  unsigned short* Kl   = (unsigned short*)(ws + 18874368);
  unsigned short* Vt   = (unsigned short*)(ws + 20971520);
  unsigned short* AOh  = (unsigned short*)(ws + 25165824);
  float* mb   = (float*)(ws + 33554432);
  float* lb   = (float*)(ws + 33685504);
  float* cur  = (float*)(ws + 33816576);
  float* bcat = (float*)(ws + 33947648);
  char* pool = ws + 33959936;
  unsigned short* hsh = (unsigned short*)pool;                 //  8,388,608
  unsigned short* hsl = (unsigned short*)(pool + 8388608);     //  8,388,608
  unsigned short* WTh = (unsigned short*)(pool + 16777216);    // 12,582,912
  unsigned short* WTl = (unsigned short*)(pool + 29360128);    // 12,582,912
  unsigned short* OTh = (unsigned short*)(pool + 41943040);    //  8,388,608
  // total ws use: 33,959,936 + 50,331,648 = 84,291,584 B (proven available R3)

  float* outp  = (float*)d_out;
  float* maskp = outp + (size_t)S * D;

  dim3 blk(256);
  // 1. all input preprocessing in one launch
  prep_all<<<dim3(3084), blk, 0, stream>>>(hs, q_w, k_w, v_w, o_w, q_b, k_b,
                                           v_b, hsh, hsl, WTh, WTl, OTh, bcat);
  // 2. QKV projection (split-bf16, global_load_lds) -> Qh/Ql/Kh/Kl/Vt direct
  gemm_qkv<<<dim3(N3 / 128, S / 128), blk, 0, stream>>>(
      hsh, hsl, WTh, WTl, bcat, Qh, Ql, Kh, Kl, Vt, S, N3, D);
  // 3. attention
  attn_mfma<<<dim3(512), blk, 0, stream>>>(Qh, Ql, Kh, Kl, Vt, AOh, mb, lb);
  // 4. cur scores + topk mask
  cur_mfma<<<dim3(512), blk, 0, stream>>>(Qh, Ql, Kh, Kl, mb, lb, cur);
  topk_kernel<<<dim3(H), blk, 0, stream>>>(cur, maskp);
  // 5. output projection
  gemm_bf16<<<dim3(D / 128, S / 128), blk, 0, stream>>>(AOh, OTh, outp, S, D, NQ);
}